// Round 7
// baseline (1274.905 us; speedup 1.0000x reference)
//
#include <hip/hip_runtime.h>
#include <cstdint>
#include <cstddef>

#define NN 8000
#define NE 128000
#define NDv 40
#define EDv 10

typedef __attribute__((ext_vector_type(8))) short short8v;
typedef __attribute__((ext_vector_type(4))) float f32x4;

__device__ __forceinline__ float rcp_fast(float x) { return __builtin_amdgcn_rcpf(x); }
__device__ __forceinline__ float sigm(float x) { return rcp_fast(1.f + __expf(-x)); }
__device__ __forceinline__ float ftanh(float x) {
    float e = __expf(2.f * x);
    return 1.f - 2.f * rcp_fast(e + 1.f);
}
__device__ __forceinline__ short f2bf(float x) {   // RNE f32 -> bf16
    unsigned u = __builtin_bit_cast(unsigned, x);
    u += 0x7fffu + ((u >> 16) & 1u);
    return (short)(u >> 16);
}
__device__ __forceinline__ float wsum(float v) {
    for (int o = 32; o; o >>= 1) v += __shfl_down(v, o);
    return v;
}
__device__ __forceinline__ float wmax(float v) {
    for (int o = 32; o; o >>= 1) v = fmaxf(v, __shfl_down(v, o));
    return v;
}

// ---------------- CSR build (per graph, edge index is static) ----------------

__global__ __launch_bounds__(256) void csr_deg_kernel(const int* __restrict__ ei, int* __restrict__ deg) {
    int e = blockIdx.x * 256 + threadIdx.x;
    if (e < NE) atomicAdd(&deg[ei[e]], 1);
}

__global__ __launch_bounds__(64) void csr_scan_kernel(const int* __restrict__ deg, int* __restrict__ off,
                                                      int* __restrict__ woff) {
    int l = threadIdx.x;
    int base = l * 125;
    int s = 0;
    for (int i = 0; i < 125; ++i) s += deg[base + i];
    int pre = s;
    for (int o = 1; o < 64; o <<= 1) { int t = __shfl_up(pre, o); if (l >= o) pre += t; }
    pre -= s;   // exclusive prefix
    int run = pre;
    for (int i = 0; i < 125; ++i) {
        off[base + i] = run; woff[base + i] = run;
        run += deg[base + i];
    }
    if (l == 63) off[NN] = run;
}

__global__ __launch_bounds__(256) void csr_fill_kernel(const int* __restrict__ ei, int* __restrict__ woff,
                                                       int* __restrict__ elist) {
    int e = blockIdx.x * 256 + threadIdx.x;
    if (e < NE) { int p = atomicAdd(&woff[ei[e]], 1); elist[p] = e; }
}

// ---------------- message passing ----------------

__global__ __launch_bounds__(256) void node_proj_kernel(const float* __restrict__ h, const float* __restrict__ Uw,
                                                        float* __restrict__ A, float* __restrict__ B) {
    int t = blockIdx.x * 256 + threadIdx.x;   // exactly 8000*40
    int n = t / NDv, i = t % NDv;
    const float* wa = Uw + i * 90;
    const float* hr = h + n * NDv;
    float a = 0.f, b = 0.f;
#pragma unroll
    for (int k = 0; k < NDv; ++k) { float hv = hr[k]; a += wa[k] * hv; b += wa[40 + k] * hv; }
    A[t] = a; B[t] = b;
}

// msg[n,i] = deg(n)*(A[n,i]+Ub[i]) + sum_{e: src=n} ( B[dst_e,i] + Uw[i,80:90]·ef[e] )
__global__ __launch_bounds__(256) void msg_gather_kernel(const int* __restrict__ off, const int* __restrict__ elist,
                                                         const int* __restrict__ ei, const float* __restrict__ ef,
                                                         const float* __restrict__ Uw, const float* __restrict__ Ub,
                                                         const float* __restrict__ A, const float* __restrict__ B,
                                                         float* __restrict__ msg) {
    int t = blockIdx.x * 256 + threadIdx.x;   // exactly 8000*40
    int n = t / NDv, i = t % NDv;
    float w[10];
    const float* we = Uw + i * 90 + 80;
#pragma unroll
    for (int k = 0; k < EDv; ++k) w[k] = we[k];
    int p0 = off[n], p1 = off[n + 1];
    float acc = (float)(p1 - p0) * (A[t] + Ub[i]);
    for (int p = p0; p < p1; ++p) {
        int e = elist[p];
        int d = ei[NE + e];
        const float* efr = ef + e * EDv;
        float s = B[d * NDv + i];
#pragma unroll
        for (int k = 0; k < EDv; ++k) s += w[k] * efr[k];
        acc += s;
    }
    msg[t] = acc;
}

__global__ __launch_bounds__(256) void node_update_kernel(const float* __restrict__ h, const float* __restrict__ msg,
                                                          const float* __restrict__ Mw, const float* __restrict__ Mb,
                                                          float* __restrict__ hout) {
    int t = blockIdx.x * 256 + threadIdx.x;   // exactly 8000*40
    int n = t / NDv, i = t % NDv;
    const float* w = Mw + i * 80;
    const float* hr = h + n * NDv;
    const float* mr = msg + n * NDv;
    float acc = Mb[i];
#pragma unroll
    for (int k = 0; k < NDv; ++k) acc += w[k] * hr[k];
#pragma unroll
    for (int k = 0; k < NDv; ++k) acc += w[40 + k] * mr[k];
    hout[t] = fmaxf(acc, 0.f);
}

// ---------------- set2set (pair, per-node LSTM h_d=40) ----------------

__global__ __launch_bounds__(256) void s2s_gates_kernel(const float* __restrict__ q, const float* __restrict__ hh,
                                                        const float* __restrict__ Wih, const float* __restrict__ Whh,
                                                        const float* __restrict__ bih, const float* __restrict__ bhh,
                                                        float* __restrict__ gatesT) {
    int t = blockIdx.x * 256 + threadIdx.x;   // exactly 8000*20
    int n = t % NN;
    int jg = t / NN;
    float qr[80];
#pragma unroll
    for (int k4 = 0; k4 < 20; ++k4) {
        float4 v = *reinterpret_cast<const float4*>(q + n * 80 + k4 * 4);
        qr[k4 * 4 + 0] = v.x; qr[k4 * 4 + 1] = v.y; qr[k4 * 4 + 2] = v.z; qr[k4 * 4 + 3] = v.w;
    }
    float hr[40];
#pragma unroll
    for (int k4 = 0; k4 < 10; ++k4) {
        float4 v = *reinterpret_cast<const float4*>(hh + n * 40 + k4 * 4);
        hr[k4 * 4 + 0] = v.x; hr[k4 * 4 + 1] = v.y; hr[k4 * 4 + 2] = v.z; hr[k4 * 4 + 3] = v.w;
    }
#pragma unroll
    for (int jj = 0; jj < 8; ++jj) {
        int j = jg * 8 + jj;
        const float* wi = Wih + j * 80;
        const float* wh = Whh + j * 40;
        float acc = bih[j] + bhh[j];
#pragma unroll
        for (int k = 0; k < 80; ++k) acc += wi[k] * qr[k];
#pragma unroll
        for (int k = 0; k < 40; ++k) acc += wh[k] * hr[k];
        gatesT[j * NN + n] = acc;
    }
}

__global__ __launch_bounds__(256) void s2s_update_kernel(const float* __restrict__ gatesT,
                                                         const float* __restrict__ h0, const float* __restrict__ ht,
                                                         float* __restrict__ hh, float* __restrict__ cc,
                                                         float* __restrict__ q) {
    int n = blockIdx.x * 256 + threadIdx.x;
    if (n >= NN) return;
    float hreg[40];
    float e0 = 0.f, e1 = 0.f;
#pragma unroll
    for (int i = 0; i < 40; ++i) {
        float gi = gatesT[i * NN + n];
        float gf = gatesT[(40 + i) * NN + n];
        float gg = gatesT[(80 + i) * NN + n];
        float go = gatesT[(120 + i) * NN + n];
        float cn = sigm(gf) * cc[n * 40 + i] + sigm(gi) * ftanh(gg);
        cc[n * 40 + i] = cn;
        float hn = sigm(go) * ftanh(cn);
        hreg[i] = hn;
        e0 += h0[n * 40 + i] * hn;
        e1 += ht[n * 40 + i] * hn;
    }
    float m = fmaxf(e0, e1);
    float p0 = __expf(e0 - m), p1 = __expf(e1 - m);
    float inv = rcp_fast(p0 + p1);
    float a0 = p0 * inv, a1 = p1 * inv;
#pragma unroll
    for (int i = 0; i < 40; ++i) {
        hh[n * 40 + i] = hreg[i];
        q[n * 80 + i] = hreg[i];
        q[n * 80 + 40 + i] = a0 * h0[n * 40 + i] + a1 * ht[n * 40 + i];
    }
}

// ---------------- bf16 casts ----------------

__global__ __launch_bounds__(256) void cast_pad_kernel(const float* __restrict__ g, short* __restrict__ o) {
    int t = blockIdx.x * 256 + threadIdx.x;   // exactly 8000*96
    int m = t / 96, k = t % 96;
    o[t] = (k < 80) ? f2bf(g[m * 80 + k]) : (short)0;
}

__global__ __launch_bounds__(256) void cast_t_kernel(const float* __restrict__ g, short* __restrict__ o) {
    int t = blockIdx.x * 256 + threadIdx.x;   // exactly 80*8000
    int m = t % NN, f = t / NN;
    o[t] = f2bf(g[m * 80 + f]);
}

// ---------------- fused interaction + after-feature (barrier-free, wave-private P) ----------------
// Each wave owns 16 X-rows. Per 64-wide Y-chunk:
//   accI = X(16 rows) @ Y(64 rows)^T      (C rows == this wave's X-rows)
//   [optionally stream accI to I]
//   P[wave] = tanh(accI) as bf16 (LDS, wave-private layout shuffle C->A)
//   acc[ft] += P @ YT(80 features)        (A rows == same 16 X-rows)
// No __syncthreads anywhere -> I stores never drain at barriers.
// grid (125 x-tiles of 64, 10 y-chunks); uneven 12/13 chunk split.

__global__ __launch_bounds__(256) void fused_kernel(const short* __restrict__ Xb, const short* __restrict__ Yb,
                                                    const short* __restrict__ YT, float* __restrict__ Iout,
                                                    float* __restrict__ afT) {
    __shared__ short P[4][16][72];   // per-wave [row][col], 144B row stride (16B-aligned)
    int tid = threadIdx.x;
    int w = tid >> 6, l = tid & 63;
    int lrow = l & 15, lk = l >> 4;
    int x0 = blockIdx.x * 64;
    int it0 = (125 * blockIdx.y) / 10;
    int it1 = (125 * (blockIdx.y + 1)) / 10;
    short8v a_x[3];
    const short* arow = Xb + (size_t)(x0 + w * 16 + lrow) * 96 + lk * 8;
#pragma unroll
    for (int ks = 0; ks < 3; ++ks) a_x[ks] = *reinterpret_cast<const short8v*>(arow + ks * 32);
    f32x4 acc[5] = {};
    for (int it = it0; it < it1; ++it) {
        int k0 = it * 64;
        f32x4 accI[4] = {};
#pragma unroll
        for (int ks = 0; ks < 3; ++ks) {
#pragma unroll
            for (int nt = 0; nt < 4; ++nt) {
                short8v b = *reinterpret_cast<const short8v*>(Yb + (size_t)(k0 + nt * 16 + lrow) * 96 + ks * 32 + lk * 8);
                accI[nt] = __builtin_amdgcn_mfma_f32_16x16x32_bf16(a_x[ks], b, accI[nt], 0, 0, 0);
            }
        }
#pragma unroll
        for (int nt = 0; nt < 4; ++nt)
#pragma unroll
            for (int r = 0; r < 4; ++r) {
                float v = accI[nt][r];
                if (Iout)
                    __builtin_nontemporal_store(v, &Iout[(size_t)(x0 + w * 16 + lk * 4 + r) * NN + (k0 + nt * 16 + lrow)]);
                P[w][lk * 4 + r][nt * 16 + lrow] = f2bf(ftanh(v));
            }
        // wave-private: in-order LDS per wave makes write->read safe without barriers
#pragma unroll
        for (int ks2 = 0; ks2 < 2; ++ks2) {
            short8v ap = *reinterpret_cast<const short8v*>(&P[w][lrow][ks2 * 32 + lk * 8]);
#pragma unroll
            for (int ft = 0; ft < 5; ++ft) {
                short8v b = *reinterpret_cast<const short8v*>(YT + (size_t)(ft * 16 + lrow) * NN + k0 + ks2 * 32 + lk * 8);
                acc[ft] = __builtin_amdgcn_mfma_f32_16x16x32_bf16(ap, b, acc[ft], 0, 0, 0);
            }
        }
    }
    int xout = x0 + w * 16 + lk * 4;
#pragma unroll
    for (int ft = 0; ft < 5; ++ft)
#pragma unroll
        for (int r = 0; r < 4; ++r)
            atomicAdd(&afT[(size_t)(ft * 16 + lrow) * NN + xout + r], acc[ft][r]);
}

// ---------------- set2set pool (batch 1, h_d=160) ----------------

__global__ __launch_bounds__(64) void gates_pool_kernel(const float* __restrict__ Wih, const float* __restrict__ Whh,
                                                        const float* __restrict__ bih, const float* __restrict__ bhh,
                                                        const float* __restrict__ q, const float* __restrict__ h,
                                                        float* __restrict__ gts) {
    int j = blockIdx.x;
    int lane = threadIdx.x;
    const float* wi = Wih + j * 320;
    const float* wh = Whh + j * 160;
    float p = 0.f;
#pragma unroll
    for (int k4 = 0; k4 < 5; ++k4) { int k = lane + k4 * 64; p += wi[k] * q[k]; }
#pragma unroll
    for (int k4 = 0; k4 < 3; ++k4) { int k = lane + k4 * 64; if (k < 160) p += wh[k] * h[k]; }
    p = wsum(p);
    if (lane == 0) gts[j] = p + bih[j] + bhh[j];
}

__global__ __launch_bounds__(256) void pool_point_kernel(const float* __restrict__ gts, float* __restrict__ h,
                                                         float* __restrict__ c, float* __restrict__ q) {
    int tid = threadIdx.x;
    if (tid < 160) {
        float cn = sigm(gts[160 + tid]) * c[tid] + sigm(gts[tid]) * ftanh(gts[320 + tid]);
        c[tid] = cn;
        float hn = sigm(gts[480 + tid]) * ftanh(cn);
        h[tid] = hn;
        q[tid] = hn;   // q_star[0:160] = h
    }
}

__global__ __launch_bounds__(256) void pool_scores_kernel(const float* __restrict__ afT, const float* __restrict__ g,
                                                          const float* __restrict__ h, float* __restrict__ scores,
                                                          float* __restrict__ pmax) {
    int tid = threadIdx.x;
    int n = blockIdx.x * 256 + tid;
    float s = -3.4e38f;
    if (n < NN) {
        float acc = 0.f;
#pragma unroll 8
        for (int k = 0; k < 80; ++k) acc += afT[k * NN + n] * h[k];
        const float* gr = g + n * 80;
#pragma unroll 8
        for (int k = 0; k < 80; ++k) acc += gr[k] * h[80 + k];
        scores[n] = acc;
        s = acc;
    }
    __shared__ float red[4];
    float m = wmax(s);
    if ((tid & 63) == 0) red[tid >> 6] = m;
    __syncthreads();
    if (tid == 0) pmax[blockIdx.x] = fmaxf(fmaxf(red[0], red[1]), fmaxf(red[2], red[3]));
}

__global__ __launch_bounds__(256) void pool_softmax_kernel(float* __restrict__ scores, const float* __restrict__ pmax,
                                                           float* __restrict__ denom) {
    int tid = threadIdx.x;
    __shared__ float sm;
    __shared__ float red[4];
    float m = (tid < 32) ? pmax[tid] : -3.4e38f;
    m = wmax(m);
    if (tid == 0) sm = m;
    __syncthreads();
    float mm = sm;
    float lsum = 0.f;
    for (int n = tid; n < NN; n += 256) {
        float e = __expf(scores[n] - mm);
        scores[n] = e;
        lsum += e;
    }
    float w = wsum(lsum);
    if ((tid & 63) == 0) red[tid >> 6] = w;
    __syncthreads();
    if (tid == 0) denom[0] = red[0] + red[1] + red[2] + red[3];
}

__global__ __launch_bounds__(256) void pool_r_kernel(const float* __restrict__ afT, const float* __restrict__ g,
                                                     const float* __restrict__ scores, const float* __restrict__ denom,
                                                     float* __restrict__ q) {
    int f = blockIdx.x;   // 0..159
    int tid = threadIdx.x;
    float acc = 0.f;
    if (f < 80) {
        const float* x = afT + (size_t)f * NN;
        for (int n = tid; n < NN; n += 256) acc += scores[n] * x[n];
    } else {
        const float* x = g + (f - 80);
        for (int n = tid; n < NN; n += 256) acc += scores[n] * x[(size_t)n * 80];
    }
    float w = wsum(acc);
    __shared__ float red[4];
    if ((tid & 63) == 0) red[tid >> 6] = w;
    __syncthreads();
    if (tid == 0) q[160 + f] = (red[0] + red[1] + red[2] + red[3]) * rcp_fast(denom[0]);
}

// ---------------- final MLP (parallel per-row GEMVs) ----------------

__global__ __launch_bounds__(640) void concat_kernel(const float* __restrict__ cu, const float* __restrict__ cv,
                                                     float* __restrict__ x0) {
    int tid = threadIdx.x;
    x0[tid] = (tid < 320) ? cu[tid] : cv[tid - 320];
}

__global__ __launch_bounds__(64) void gemv_kernel(const float* __restrict__ W, const float* __restrict__ b,
                                                  const float* __restrict__ x, float* __restrict__ y,
                                                  int K, int relu) {
    int j = blockIdx.x;
    int lane = threadIdx.x;
    const float* w = W + (size_t)j * K;
    float p = 0.f;
    for (int k = lane; k < K; k += 64) p += w[k] * x[k];
    p = wsum(p);
    if (lane == 0) {
        p += b[j];
        y[j] = relu ? fmaxf(p, 0.f) : p;
    }
}

// ---------------- launch ----------------

extern "C" void kernel_launch(void* const* d_in, const int* in_sizes, int n_in,
                              void* d_out, int out_size, void* d_ws, size_t ws_size,
                              hipStream_t stream) {
    const float* nodes_u = (const float*)d_in[0];
    const int* ei_u = (const int*)d_in[1];
    const float* ef_u = (const float*)d_in[2];
    const float* nodes_v = (const float*)d_in[3];
    const int* ei_v = (const int*)d_in[4];
    const float* ef_v = (const float*)d_in[5];
    const float* Uw_u = (const float*)d_in[6];
    const float* Ub_u = (const float*)d_in[7];
    const float* Mw_u = (const float*)d_in[8];
    const float* Mb_u = (const float*)d_in[9];
    const float* Uw_v = (const float*)d_in[10];
    const float* Ub_v = (const float*)d_in[11];
    const float* Mw_v = (const float*)d_in[12];
    const float* Mb_v = (const float*)d_in[13];
    const float* lsWih = (const float*)d_in[14];
    const float* lsWhh = (const float*)d_in[15];
    const float* lsbih = (const float*)d_in[16];
    const float* lsbhh = (const float*)d_in[17];
    const float* lvWih = (const float*)d_in[18];
    const float* lvWhh = (const float*)d_in[19];
    const float* lvbih = (const float*)d_in[20];
    const float* lvbhh = (const float*)d_in[21];
    const float* gsWih = (const float*)d_in[22];
    const float* gsWhh = (const float*)d_in[23];
    const float* gsbih = (const float*)d_in[24];
    const float* gsbhh = (const float*)d_in[25];
    const float* gvWih = (const float*)d_in[26];
    const float* gvWhh = (const float*)d_in[27];
    const float* gvbih = (const float*)d_in[28];
    const float* gvbhh = (const float*)d_in[29];
    const float* w1 = (const float*)d_in[30];
    const float* b1 = (const float*)d_in[31];
    const float* w2 = (const float*)d_in[32];
    const float* b2 = (const float*)d_in[33];
    const float* w3 = (const float*)d_in[34];
    const float* b3 = (const float*)d_in[35];
    const float* w4 = (const float*)d_in[36];
    const float* b4 = (const float*)d_in[37];

    float* ws = (float*)d_ws;
    float* hA_u = ws + 0;
    float* hB_u = ws + 320000;
    float* hA_v = ws + 640000;
    float* hB_v = ws + 960000;
    float* msg  = ws + 1280000;
    float* Apro = ws + 1600000;
    float* Bpro = ws + 1920000;
    float* q_u  = ws + 2240000;   // gu [8000,80]
    float* q_v  = ws + 2880000;   // gv [8000,80]
    float* hh   = ws + 3520000;
    float* cc   = ws + 3840000;
    float* gT   = ws + 4160000;   // gates transposed [160][8000]
    float* uafT = ws + 5440000;   // [80][8000]
    float* vafT = ws + 6080000;   // [80][8000]
    float* scores = ws + 6720000;
    float* pmax = ws + 6728000;
    float* pden = ws + 6728032;
    float* pq_u = ws + 6728040;
    float* ph_u = ws + 6728360;
    float* pc_u = ws + 6728520;
    float* pq_v = ws + 6728680;
    float* ph_v = ws + 6729000;
    float* pc_v = ws + 6729160;
    float* pgts = ws + 6729320;   // 640
    float* mx0  = ws + 6729960;   // 640
    float* mx1  = ws + 6730600;   // 360
    float* mx2  = ws + 6730960;   // 200
    float* mx3  = ws + 6731160;   // 120
    int* ioff_u   = (int*)(ws + 6731280);   // 8001 (pad 8064)
    int* ielist_u = (int*)(ws + 6739344);   // 128000
    int* ioff_v   = (int*)(ws + 6867344);   // 8064
    int* ielist_v = (int*)(ws + 6875408);   // 128000
    int* iwoff    = (int*)(ws + 7003408);   // 8064
    int* ideg     = (int*)(ws + 7011472);   // 8064

    // bf16 buffers reuse the (dead by then) message-passing region
    short* guT = (short*)(ws + 0);        // [80][8000]
    short* gvT = (short*)(ws + 320000);   // [80][8000]
    short* gub = (short*)(ws + 640000);   // [8000][96]
    short* gvb = (short*)(ws + 1024000);  // [8000][96]

    float* out = (float*)d_out;
    float* inter = out + 1;

    // ---- CSR build: u ----
    hipMemsetAsync(ideg, 0, NN * sizeof(int), stream);
    csr_deg_kernel<<<500, 256, 0, stream>>>(ei_u, ideg);
    csr_scan_kernel<<<1, 64, 0, stream>>>(ideg, ioff_u, iwoff);
    csr_fill_kernel<<<500, 256, 0, stream>>>(ei_u, iwoff, ielist_u);
    // ---- CSR build: v ----
    hipMemsetAsync(ideg, 0, NN * sizeof(int), stream);
    csr_deg_kernel<<<500, 256, 0, stream>>>(ei_v, ideg);
    csr_scan_kernel<<<1, 64, 0, stream>>>(ideg, ioff_v, iwoff);
    csr_fill_kernel<<<500, 256, 0, stream>>>(ei_v, iwoff, ielist_v);

    // ---- message passing: u ----
    {
        const float* cur = nodes_u;
        float* nxt[3] = {hA_u, hB_u, hA_u};
        for (int k = 0; k < 3; ++k) {
            node_proj_kernel<<<1250, 256, 0, stream>>>(cur, Uw_u + k * 3600, Apro, Bpro);
            msg_gather_kernel<<<1250, 256, 0, stream>>>(ioff_u, ielist_u, ei_u, ef_u, Uw_u + k * 3600,
                                                        Ub_u + k * 40, Apro, Bpro, msg);
            node_update_kernel<<<1250, 256, 0, stream>>>(cur, msg, Mw_u + k * 3200, Mb_u + k * 40, nxt[k]);
            cur = nxt[k];
        }
    }
    // ---- message passing: v ----
    {
        const float* cur = nodes_v;
        float* nxt[3] = {hA_v, hB_v, hA_v};
        for (int k = 0; k < 3; ++k) {
            node_proj_kernel<<<1250, 256, 0, stream>>>(cur, Uw_v + k * 3600, Apro, Bpro);
            msg_gather_kernel<<<1250, 256, 0, stream>>>(ioff_v, ielist_v, ei_v, ef_v, Uw_v + k * 3600,
                                                        Ub_v + k * 40, Apro, Bpro, msg);
            node_update_kernel<<<1250, 256, 0, stream>>>(cur, msg, Mw_v + k * 3200, Mb_v + k * 40, nxt[k]);
            cur = nxt[k];
        }
    }

    // ---- set2set pair ----
    hipMemsetAsync(q_u, 0, 640000 * sizeof(float), stream);
    hipMemsetAsync(hh, 0, 640000 * sizeof(float), stream);   // hh + cc contiguous
    for (int stp = 0; stp < 2; ++stp) {
        s2s_gates_kernel<<<625, 256, 0, stream>>>(q_u, hh, lsWih, lsWhh, lsbih, lsbhh, gT);
        s2s_update_kernel<<<32, 256, 0, stream>>>(gT, nodes_u, hA_u, hh, cc, q_u);
    }
    hipMemsetAsync(q_v, 0, 640000 * sizeof(float), stream);
    hipMemsetAsync(hh, 0, 640000 * sizeof(float), stream);
    for (int stp = 0; stp < 2; ++stp) {
        s2s_gates_kernel<<<625, 256, 0, stream>>>(q_v, hh, lvWih, lvWhh, lvbih, lvbhh, gT);
        s2s_update_kernel<<<32, 256, 0, stream>>>(gT, nodes_v, hA_v, hh, cc, q_v);
    }

    // ---- bf16 casts ----
    cast_t_kernel<<<2500, 256, 0, stream>>>(q_u, guT);
    cast_t_kernel<<<2500, 256, 0, stream>>>(q_v, gvT);
    cast_pad_kernel<<<3000, 256, 0, stream>>>(q_u, gub);
    cast_pad_kernel<<<3000, 256, 0, stream>>>(q_v, gvb);

    // ---- fused interaction + after-features (barrier-free) ----
    hipMemsetAsync(uafT, 0, 1280000 * sizeof(float), stream);   // uafT + vafT contiguous
    fused_kernel<<<dim3(125, 10), 256, 0, stream>>>(gub, gvb, gvT, inter, uafT);      // I + u_afterT
    fused_kernel<<<dim3(125, 10), 256, 0, stream>>>(gvb, gub, guT, nullptr, vafT);    // I^T recompute + v_afterT

    // ---- pools ----
    hipMemsetAsync(pq_u, 0, 640 * sizeof(float), stream);   // pq+ph+pc contiguous
    for (int stp = 0; stp < 2; ++stp) {
        gates_pool_kernel<<<640, 64, 0, stream>>>(gsWih, gsWhh, gsbih, gsbhh, pq_u, ph_u, pgts);
        pool_point_kernel<<<1, 256, 0, stream>>>(pgts, ph_u, pc_u, pq_u);
        pool_scores_kernel<<<32, 256, 0, stream>>>(uafT, q_u, ph_u, scores, pmax);
        pool_softmax_kernel<<<1, 256, 0, stream>>>(scores, pmax, pden);
        pool_r_kernel<<<160, 256, 0, stream>>>(uafT, q_u, scores, pden, pq_u);
    }
    hipMemsetAsync(pq_v, 0, 640 * sizeof(float), stream);
    for (int stp = 0; stp < 2; ++stp) {
        gates_pool_kernel<<<640, 64, 0, stream>>>(gvWih, gvWhh, gvbih, gvbhh, pq_v, ph_v, pgts);
        pool_point_kernel<<<1, 256, 0, stream>>>(pgts, ph_v, pc_v, pq_v);
        pool_scores_kernel<<<32, 256, 0, stream>>>(vafT, q_v, ph_v, scores, pmax);
        pool_softmax_kernel<<<1, 256, 0, stream>>>(scores, pmax, pden);
        pool_r_kernel<<<160, 256, 0, stream>>>(vafT, q_v, scores, pden, pq_v);
    }

    // ---- final MLP ----
    concat_kernel<<<1, 640, 0, stream>>>(pq_u, pq_v, mx0);
    gemv_kernel<<<360, 64, 0, stream>>>(w1, b1, mx0, mx1, 640, 1);
    gemv_kernel<<<200, 64, 0, stream>>>(w2, b2, mx1, mx2, 360, 1);
    gemv_kernel<<<120, 64, 0, stream>>>(w3, b3, mx2, mx3, 200, 1);
    gemv_kernel<<<1, 64, 0, stream>>>(w4, b4, mx3, out, 120, 0);
}

// Round 8
// 1043.041 us; speedup vs baseline: 1.2223x; 1.2223x over previous
//
#include <hip/hip_runtime.h>
#include <cstdint>
#include <cstddef>

#define NN 8000
#define NE 128000
#define NDv 40
#define EDv 10

typedef __attribute__((ext_vector_type(8))) short short8v;
typedef __attribute__((ext_vector_type(4))) float f32x4;

__device__ __forceinline__ float rcp_fast(float x) { return __builtin_amdgcn_rcpf(x); }
__device__ __forceinline__ float sigm(float x) { return rcp_fast(1.f + __expf(-x)); }
__device__ __forceinline__ float ftanh(float x) {
    float e = __expf(2.f * x);
    return 1.f - 2.f * rcp_fast(e + 1.f);
}
__device__ __forceinline__ short f2bf(float x) {   // RNE f32 -> bf16
    unsigned u = __builtin_bit_cast(unsigned, x);
    u += 0x7fffu + ((u >> 16) & 1u);
    return (short)(u >> 16);
}
__device__ __forceinline__ float wsum(float v) {
    for (int o = 32; o; o >>= 1) v += __shfl_down(v, o);
    return v;
}
__device__ __forceinline__ float wmax(float v) {
    for (int o = 32; o; o >>= 1) v = fmaxf(v, __shfl_down(v, o));
    return v;
}

// ---------------- CSR build (per graph, edge index is static) ----------------

__global__ __launch_bounds__(256) void csr_deg_kernel(const int* __restrict__ ei, int* __restrict__ deg) {
    int e = blockIdx.x * 256 + threadIdx.x;
    if (e < NE) atomicAdd(&deg[ei[e]], 1);
}

__global__ __launch_bounds__(64) void csr_scan_kernel(const int* __restrict__ deg, int* __restrict__ off,
                                                      int* __restrict__ woff) {
    int l = threadIdx.x;
    int base = l * 125;
    int s = 0;
    for (int i = 0; i < 125; ++i) s += deg[base + i];
    int pre = s;
    for (int o = 1; o < 64; o <<= 1) { int t = __shfl_up(pre, o); if (l >= o) pre += t; }
    pre -= s;   // exclusive prefix
    int run = pre;
    for (int i = 0; i < 125; ++i) {
        off[base + i] = run; woff[base + i] = run;
        run += deg[base + i];
    }
    if (l == 63) off[NN] = run;
}

// store DESTINATION node id per CSR slot (not edge id)
__global__ __launch_bounds__(256) void csr_fill_kernel(const int* __restrict__ ei, int* __restrict__ woff,
                                                       int* __restrict__ dlist) {
    int e = blockIdx.x * 256 + threadIdx.x;
    if (e < NE) { int p = atomicAdd(&woff[ei[e]], 1); dlist[p] = ei[NE + e]; }
}

// sef[n,k] = sum_{e: src=n} ef[e,k]   (round-independent, once per graph)
__global__ __launch_bounds__(256) void sef_kernel(const int* __restrict__ ei, const float* __restrict__ ef,
                                                  float* __restrict__ sef) {
    int t = blockIdx.x * 256 + threadIdx.x;   // exactly NE*EDv
    int e = t / EDv, k = t % EDv;
    atomicAdd(&sef[ei[e] * EDv + k], ef[t]);
}

// ---------------- message passing ----------------

__global__ __launch_bounds__(256) void node_proj_kernel(const float* __restrict__ h, const float* __restrict__ Uw,
                                                        float* __restrict__ A, float* __restrict__ B) {
    __shared__ float W[40][81];   // Uw[i][0:80], 81-pad -> conflict-free strided reads
    int tid = threadIdx.x;
    for (int s = tid; s < 3200; s += 256) W[s / 80][s % 80] = Uw[(s / 80) * 90 + (s % 80)];
    __syncthreads();
    int t = blockIdx.x * 256 + tid;   // exactly 8000*40
    int n = t / NDv, i = t % NDv;
    float hreg[40];
    const float* hr = h + n * NDv;
#pragma unroll
    for (int k4 = 0; k4 < 10; ++k4) {
        float4 v = *reinterpret_cast<const float4*>(hr + k4 * 4);
        hreg[k4 * 4 + 0] = v.x; hreg[k4 * 4 + 1] = v.y; hreg[k4 * 4 + 2] = v.z; hreg[k4 * 4 + 3] = v.w;
    }
    float a = 0.f, b = 0.f;
#pragma unroll
    for (int k = 0; k < NDv; ++k) { a += W[i][k] * hreg[k]; b += W[i][40 + k] * hreg[k]; }
    A[t] = a; B[t] = b;
}

// msg[n,i] = deg*(A[n,i]+Ub[i]) + Uw[i,80:90]·sef[n] + sum_p B[dlist[p],i]
__global__ __launch_bounds__(256) void msg_gather_kernel(const int* __restrict__ off, const int* __restrict__ dlist,
                                                         const float* __restrict__ sef,
                                                         const float* __restrict__ Uw, const float* __restrict__ Ub,
                                                         const float* __restrict__ A, const float* __restrict__ B,
                                                         float* __restrict__ msg) {
    int t = blockIdx.x * 256 + threadIdx.x;   // exactly 8000*40
    int n = t / NDv, i = t % NDv;
    const float* we = Uw + i * 90 + 80;
    const float* se = sef + n * EDv;
    int p0 = off[n], p1 = off[n + 1];
    float acc = (float)(p1 - p0) * (A[t] + Ub[i]);
#pragma unroll
    for (int k = 0; k < EDv; ++k) acc += we[k] * se[k];
    for (int p = p0; p < p1; ++p) acc += B[dlist[p] * NDv + i];
    msg[t] = acc;
}

__global__ __launch_bounds__(256) void node_update_kernel(const float* __restrict__ h, const float* __restrict__ msg,
                                                          const float* __restrict__ Mw, const float* __restrict__ Mb,
                                                          float* __restrict__ hout) {
    __shared__ float W[40][81];   // Mw[i][0:80]
    int tid = threadIdx.x;
    for (int s = tid; s < 3200; s += 256) W[s / 80][s % 80] = Mw[s];
    __syncthreads();
    int t = blockIdx.x * 256 + tid;   // exactly 8000*40
    int n = t / NDv, i = t % NDv;
    const float* hr = h + n * NDv;
    const float* mr = msg + n * NDv;
    float acc = Mb[i];
#pragma unroll
    for (int k = 0; k < NDv; ++k) acc += W[i][k] * hr[k];
#pragma unroll
    for (int k = 0; k < NDv; ++k) acc += W[i][40 + k] * mr[k];
    hout[t] = fmaxf(acc, 0.f);
}

// ---------------- set2set (pair, per-node LSTM h_d=40) ----------------

__global__ __launch_bounds__(256) void s2s_gates_kernel(const float* __restrict__ q, const float* __restrict__ hh,
                                                        const float* __restrict__ Wih, const float* __restrict__ Whh,
                                                        const float* __restrict__ bih, const float* __restrict__ bhh,
                                                        float* __restrict__ gatesT) {
    int t = blockIdx.x * 256 + threadIdx.x;   // exactly 8000*20
    int n = t % NN;
    int jg = t / NN;
    float qr[80];
#pragma unroll
    for (int k4 = 0; k4 < 20; ++k4) {
        float4 v = *reinterpret_cast<const float4*>(q + n * 80 + k4 * 4);
        qr[k4 * 4 + 0] = v.x; qr[k4 * 4 + 1] = v.y; qr[k4 * 4 + 2] = v.z; qr[k4 * 4 + 3] = v.w;
    }
    float hr[40];
#pragma unroll
    for (int k4 = 0; k4 < 10; ++k4) {
        float4 v = *reinterpret_cast<const float4*>(hh + n * 40 + k4 * 4);
        hr[k4 * 4 + 0] = v.x; hr[k4 * 4 + 1] = v.y; hr[k4 * 4 + 2] = v.z; hr[k4 * 4 + 3] = v.w;
    }
#pragma unroll
    for (int jj = 0; jj < 8; ++jj) {
        int j = jg * 8 + jj;
        const float* wi = Wih + j * 80;
        const float* wh = Whh + j * 40;
        float acc = bih[j] + bhh[j];
#pragma unroll
        for (int k = 0; k < 80; ++k) acc += wi[k] * qr[k];
#pragma unroll
        for (int k = 0; k < 40; ++k) acc += wh[k] * hr[k];
        gatesT[j * NN + n] = acc;
    }
}

__global__ __launch_bounds__(256) void s2s_update_kernel(const float* __restrict__ gatesT,
                                                         const float* __restrict__ h0, const float* __restrict__ ht,
                                                         float* __restrict__ hh, float* __restrict__ cc,
                                                         float* __restrict__ q) {
    int n = blockIdx.x * 256 + threadIdx.x;
    if (n >= NN) return;
    float hreg[40];
    float e0 = 0.f, e1 = 0.f;
#pragma unroll
    for (int i = 0; i < 40; ++i) {
        float gi = gatesT[i * NN + n];
        float gf = gatesT[(40 + i) * NN + n];
        float gg = gatesT[(80 + i) * NN + n];
        float go = gatesT[(120 + i) * NN + n];
        float cn = sigm(gf) * cc[n * 40 + i] + sigm(gi) * ftanh(gg);
        cc[n * 40 + i] = cn;
        float hn = sigm(go) * ftanh(cn);
        hreg[i] = hn;
        e0 += h0[n * 40 + i] * hn;
        e1 += ht[n * 40 + i] * hn;
    }
    float m = fmaxf(e0, e1);
    float p0 = __expf(e0 - m), p1 = __expf(e1 - m);
    float inv = rcp_fast(p0 + p1);
    float a0 = p0 * inv, a1 = p1 * inv;
#pragma unroll
    for (int i = 0; i < 40; ++i) {
        hh[n * 40 + i] = hreg[i];
        q[n * 80 + i] = hreg[i];
        q[n * 80 + 40 + i] = a0 * h0[n * 40 + i] + a1 * ht[n * 40 + i];
    }
}

// ---------------- bf16 casts ----------------

__global__ __launch_bounds__(256) void cast_pad_kernel(const float* __restrict__ g, short* __restrict__ o) {
    int t = blockIdx.x * 256 + threadIdx.x;   // exactly 8000*96
    int m = t / 96, k = t % 96;
    o[t] = (k < 80) ? f2bf(g[m * 80 + k]) : (short)0;
}

__global__ __launch_bounds__(256) void cast_t_kernel(const float* __restrict__ g, short* __restrict__ o) {
    int t = blockIdx.x * 256 + threadIdx.x;   // exactly 80*8000
    int m = t % NN, f = t / NN;
    o[t] = f2bf(g[m * 80 + f]);
}

// ---------------- fused interaction + after-feature (barrier-free, wave-private P) ----------------
// Each wave owns 16 X-rows. Per 64-wide Y-chunk:
//   accI = X(16 rows) @ Y(64 rows)^T  -> [plain store to I]  -> P=tanh bf16 (wave-private LDS)
//   acc[ft] += P @ YT
// grid (125 x-tiles, 8 y-chunks of 15-16). NO __syncthreads -> I stores never drain at a barrier.
// NOTE: plain stores (NOT nontemporal) — L2 write-allocate merges the 4x64B row segments.

__global__ __launch_bounds__(256) void fused_kernel(const short* __restrict__ Xb, const short* __restrict__ Yb,
                                                    const short* __restrict__ YT, float* __restrict__ Iout,
                                                    float* __restrict__ afT) {
    __shared__ short P[4][16][72];   // per-wave [row][col], 144B row stride
    int tid = threadIdx.x;
    int w = tid >> 6, l = tid & 63;
    int lrow = l & 15, lk = l >> 4;
    int x0 = blockIdx.x * 64;
    int it0 = (125 * blockIdx.y) >> 3;
    int it1 = (125 * (blockIdx.y + 1)) >> 3;
    short8v a_x[3];
    const short* arow = Xb + (size_t)(x0 + w * 16 + lrow) * 96 + lk * 8;
#pragma unroll
    for (int ks = 0; ks < 3; ++ks) a_x[ks] = *reinterpret_cast<const short8v*>(arow + ks * 32);
    f32x4 acc[5] = {};
    for (int it = it0; it < it1; ++it) {
        int k0 = it * 64;
        f32x4 accI[4] = {};
#pragma unroll
        for (int ks = 0; ks < 3; ++ks) {
#pragma unroll
            for (int nt = 0; nt < 4; ++nt) {
                short8v b = *reinterpret_cast<const short8v*>(Yb + (size_t)(k0 + nt * 16 + lrow) * 96 + ks * 32 + lk * 8);
                accI[nt] = __builtin_amdgcn_mfma_f32_16x16x32_bf16(a_x[ks], b, accI[nt], 0, 0, 0);
            }
        }
#pragma unroll
        for (int nt = 0; nt < 4; ++nt)
#pragma unroll
            for (int r = 0; r < 4; ++r) {
                float v = accI[nt][r];
                if (Iout)
                    Iout[(size_t)(x0 + w * 16 + lk * 4 + r) * NN + (k0 + nt * 16 + lrow)] = v;
                P[w][lk * 4 + r][nt * 16 + lrow] = f2bf(ftanh(v));
            }
        // wave-private LDS: same-wave write->read is in-order, no barrier needed
#pragma unroll
        for (int ks2 = 0; ks2 < 2; ++ks2) {
            short8v ap = *reinterpret_cast<const short8v*>(&P[w][lrow][ks2 * 32 + lk * 8]);
#pragma unroll
            for (int ft = 0; ft < 5; ++ft) {
                short8v b = *reinterpret_cast<const short8v*>(YT + (size_t)(ft * 16 + lrow) * NN + k0 + ks2 * 32 + lk * 8);
                acc[ft] = __builtin_amdgcn_mfma_f32_16x16x32_bf16(ap, b, acc[ft], 0, 0, 0);
            }
        }
    }
    int xout = x0 + w * 16 + lk * 4;
#pragma unroll
    for (int ft = 0; ft < 5; ++ft)
#pragma unroll
        for (int r = 0; r < 4; ++r)
            atomicAdd(&afT[(size_t)(ft * 16 + lrow) * NN + xout + r], acc[ft][r]);
}

// ---------------- set2set pool (batch 1, h_d=160) ----------------

__global__ __launch_bounds__(64) void gates_pool_kernel(const float* __restrict__ Wih, const float* __restrict__ Whh,
                                                        const float* __restrict__ bih, const float* __restrict__ bhh,
                                                        const float* __restrict__ q, const float* __restrict__ h,
                                                        float* __restrict__ gts) {
    int j = blockIdx.x;
    int lane = threadIdx.x;
    const float* wi = Wih + j * 320;
    const float* wh = Whh + j * 160;
    float p = 0.f;
#pragma unroll
    for (int k4 = 0; k4 < 5; ++k4) { int k = lane + k4 * 64; p += wi[k] * q[k]; }
#pragma unroll
    for (int k4 = 0; k4 < 3; ++k4) { int k = lane + k4 * 64; if (k < 160) p += wh[k] * h[k]; }
    p = wsum(p);
    if (lane == 0) gts[j] = p + bih[j] + bhh[j];
}

__global__ __launch_bounds__(256) void pool_point_kernel(const float* __restrict__ gts, float* __restrict__ h,
                                                         float* __restrict__ c, float* __restrict__ q) {
    int tid = threadIdx.x;
    if (tid < 160) {
        float cn = sigm(gts[160 + tid]) * c[tid] + sigm(gts[tid]) * ftanh(gts[320 + tid]);
        c[tid] = cn;
        float hn = sigm(gts[480 + tid]) * ftanh(cn);
        h[tid] = hn;
        q[tid] = hn;   // q_star[0:160] = h
    }
}

__global__ __launch_bounds__(256) void pool_scores_kernel(const float* __restrict__ afT, const float* __restrict__ g,
                                                          const float* __restrict__ h, float* __restrict__ scores,
                                                          float* __restrict__ pmax) {
    int tid = threadIdx.x;
    int n = blockIdx.x * 256 + tid;
    float s = -3.4e38f;
    if (n < NN) {
        float acc = 0.f;
#pragma unroll 8
        for (int k = 0; k < 80; ++k) acc += afT[k * NN + n] * h[k];
        const float* gr = g + n * 80;
#pragma unroll 8
        for (int k = 0; k < 80; ++k) acc += gr[k] * h[80 + k];
        scores[n] = acc;
        s = acc;
    }
    __shared__ float red[4];
    float m = wmax(s);
    if ((tid & 63) == 0) red[tid >> 6] = m;
    __syncthreads();
    if (tid == 0) pmax[blockIdx.x] = fmaxf(fmaxf(red[0], red[1]), fmaxf(red[2], red[3]));
}

__global__ __launch_bounds__(256) void pool_softmax_kernel(float* __restrict__ scores, const float* __restrict__ pmax,
                                                           float* __restrict__ denom) {
    int tid = threadIdx.x;
    __shared__ float sm;
    __shared__ float red[4];
    float m = (tid < 32) ? pmax[tid] : -3.4e38f;
    m = wmax(m);
    if (tid == 0) sm = m;
    __syncthreads();
    float mm = sm;
    float lsum = 0.f;
    for (int n = tid; n < NN; n += 256) {
        float e = __expf(scores[n] - mm);
        scores[n] = e;
        lsum += e;
    }
    float w = wsum(lsum);
    if ((tid & 63) == 0) red[tid >> 6] = w;
    __syncthreads();
    if (tid == 0) denom[0] = red[0] + red[1] + red[2] + red[3];
}

__global__ __launch_bounds__(256) void pool_r_kernel(const float* __restrict__ afT, const float* __restrict__ g,
                                                     const float* __restrict__ scores, const float* __restrict__ denom,
                                                     float* __restrict__ q) {
    int f = blockIdx.x;   // 0..159
    int tid = threadIdx.x;
    float acc = 0.f;
    if (f < 80) {
        const float* x = afT + (size_t)f * NN;
        for (int n = tid; n < NN; n += 256) acc += scores[n] * x[n];
    } else {
        const float* x = g + (f - 80);
        for (int n = tid; n < NN; n += 256) acc += scores[n] * x[(size_t)n * 80];
    }
    float w = wsum(acc);
    __shared__ float red[4];
    if ((tid & 63) == 0) red[tid >> 6] = w;
    __syncthreads();
    if (tid == 0) q[160 + f] = (red[0] + red[1] + red[2] + red[3]) * rcp_fast(denom[0]);
}

// ---------------- final MLP (parallel per-row GEMVs) ----------------

__global__ __launch_bounds__(640) void concat_kernel(const float* __restrict__ cu, const float* __restrict__ cv,
                                                     float* __restrict__ x0) {
    int tid = threadIdx.x;
    x0[tid] = (tid < 320) ? cu[tid] : cv[tid - 320];
}

__global__ __launch_bounds__(64) void gemv_kernel(const float* __restrict__ W, const float* __restrict__ b,
                                                  const float* __restrict__ x, float* __restrict__ y,
                                                  int K, int relu) {
    int j = blockIdx.x;
    int lane = threadIdx.x;
    const float* w = W + (size_t)j * K;
    float p = 0.f;
    for (int k = lane; k < K; k += 64) p += w[k] * x[k];
    p = wsum(p);
    if (lane == 0) {
        p += b[j];
        y[j] = relu ? fmaxf(p, 0.f) : p;
    }
}

// ---------------- launch ----------------

extern "C" void kernel_launch(void* const* d_in, const int* in_sizes, int n_in,
                              void* d_out, int out_size, void* d_ws, size_t ws_size,
                              hipStream_t stream) {
    const float* nodes_u = (const float*)d_in[0];
    const int* ei_u = (const int*)d_in[1];
    const float* ef_u = (const float*)d_in[2];
    const float* nodes_v = (const float*)d_in[3];
    const int* ei_v = (const int*)d_in[4];
    const float* ef_v = (const float*)d_in[5];
    const float* Uw_u = (const float*)d_in[6];
    const float* Ub_u = (const float*)d_in[7];
    const float* Mw_u = (const float*)d_in[8];
    const float* Mb_u = (const float*)d_in[9];
    const float* Uw_v = (const float*)d_in[10];
    const float* Ub_v = (const float*)d_in[11];
    const float* Mw_v = (const float*)d_in[12];
    const float* Mb_v = (const float*)d_in[13];
    const float* lsWih = (const float*)d_in[14];
    const float* lsWhh = (const float*)d_in[15];
    const float* lsbih = (const float*)d_in[16];
    const float* lsbhh = (const float*)d_in[17];
    const float* lvWih = (const float*)d_in[18];
    const float* lvWhh = (const float*)d_in[19];
    const float* lvbih = (const float*)d_in[20];
    const float* lvbhh = (const float*)d_in[21];
    const float* gsWih = (const float*)d_in[22];
    const float* gsWhh = (const float*)d_in[23];
    const float* gsbih = (const float*)d_in[24];
    const float* gsbhh = (const float*)d_in[25];
    const float* gvWih = (const float*)d_in[26];
    const float* gvWhh = (const float*)d_in[27];
    const float* gvbih = (const float*)d_in[28];
    const float* gvbhh = (const float*)d_in[29];
    const float* w1 = (const float*)d_in[30];
    const float* b1 = (const float*)d_in[31];
    const float* w2 = (const float*)d_in[32];
    const float* b2 = (const float*)d_in[33];
    const float* w3 = (const float*)d_in[34];
    const float* b3 = (const float*)d_in[35];
    const float* w4 = (const float*)d_in[36];
    const float* b4 = (const float*)d_in[37];

    float* ws = (float*)d_ws;
    float* hA_u = ws + 0;
    float* hB_u = ws + 320000;
    float* hA_v = ws + 640000;
    float* hB_v = ws + 960000;
    float* msg  = ws + 1280000;
    float* Apro = ws + 1600000;
    float* Bpro = ws + 1920000;
    float* q_u  = ws + 2240000;   // gu [8000,80]
    float* q_v  = ws + 2880000;   // gv [8000,80]
    float* hh   = ws + 3520000;
    float* cc   = ws + 3840000;
    float* gT   = ws + 4160000;   // gates transposed [160][8000] (s2s phase only)
    float* sef_u = ws + 4160000;  // [8000][10] — dead before s2s starts
    float* sef_v = ws + 4240000;  // [8000][10]
    float* uafT = ws + 5440000;   // [80][8000]
    float* vafT = ws + 6080000;   // [80][8000]
    float* scores = ws + 6720000;
    float* pmax = ws + 6728000;
    float* pden = ws + 6728032;
    float* pq_u = ws + 6728040;
    float* ph_u = ws + 6728360;
    float* pc_u = ws + 6728520;
    float* pq_v = ws + 6728680;
    float* ph_v = ws + 6729000;
    float* pc_v = ws + 6729160;
    float* pgts = ws + 6729320;   // 640
    float* mx0  = ws + 6729960;   // 640
    float* mx1  = ws + 6730600;   // 360
    float* mx2  = ws + 6730960;   // 200
    float* mx3  = ws + 6731160;   // 120
    int* ioff_u   = (int*)(ws + 6731280);   // 8001 (pad 8064)
    int* idlist_u = (int*)(ws + 6739344);   // 128000
    int* ioff_v   = (int*)(ws + 6867344);   // 8064
    int* idlist_v = (int*)(ws + 6875408);   // 128000
    int* iwoff    = (int*)(ws + 7003408);   // 8064
    int* ideg     = (int*)(ws + 7011472);   // 8064

    // bf16 buffers reuse the (dead by then) message-passing region
    short* guT = (short*)(ws + 0);        // [80][8000]
    short* gvT = (short*)(ws + 320000);   // [80][8000]
    short* gub = (short*)(ws + 640000);   // [8000][96]
    short* gvb = (short*)(ws + 1024000);  // [8000][96]

    float* out = (float*)d_out;
    float* inter = out + 1;

    // ---- CSR + edge-feature sums: u ----
    hipMemsetAsync(ideg, 0, NN * sizeof(int), stream);
    hipMemsetAsync(sef_u, 0, NN * EDv * sizeof(float), stream);
    csr_deg_kernel<<<500, 256, 0, stream>>>(ei_u, ideg);
    csr_scan_kernel<<<1, 64, 0, stream>>>(ideg, ioff_u, iwoff);
    csr_fill_kernel<<<500, 256, 0, stream>>>(ei_u, iwoff, idlist_u);
    sef_kernel<<<5000, 256, 0, stream>>>(ei_u, ef_u, sef_u);
    // ---- CSR + edge-feature sums: v ----
    hipMemsetAsync(ideg, 0, NN * sizeof(int), stream);
    hipMemsetAsync(sef_v, 0, NN * EDv * sizeof(float), stream);
    csr_deg_kernel<<<500, 256, 0, stream>>>(ei_v, ideg);
    csr_scan_kernel<<<1, 64, 0, stream>>>(ideg, ioff_v, iwoff);
    csr_fill_kernel<<<500, 256, 0, stream>>>(ei_v, iwoff, idlist_v);
    sef_kernel<<<5000, 256, 0, stream>>>(ei_v, ef_v, sef_v);

    // ---- message passing: u ----
    {
        const float* cur = nodes_u;
        float* nxt[3] = {hA_u, hB_u, hA_u};
        for (int k = 0; k < 3; ++k) {
            node_proj_kernel<<<1250, 256, 0, stream>>>(cur, Uw_u + k * 3600, Apro, Bpro);
            msg_gather_kernel<<<1250, 256, 0, stream>>>(ioff_u, idlist_u, sef_u, Uw_u + k * 3600,
                                                        Ub_u + k * 40, Apro, Bpro, msg);
            node_update_kernel<<<1250, 256, 0, stream>>>(cur, msg, Mw_u + k * 3200, Mb_u + k * 40, nxt[k]);
            cur = nxt[k];
        }
    }
    // ---- message passing: v ----
    {
        const float* cur = nodes_v;
        float* nxt[3] = {hA_v, hB_v, hA_v};
        for (int k = 0; k < 3; ++k) {
            node_proj_kernel<<<1250, 256, 0, stream>>>(cur, Uw_v + k * 3600, Apro, Bpro);
            msg_gather_kernel<<<1250, 256, 0, stream>>>(ioff_v, idlist_v, sef_v, Uw_v + k * 3600,
                                                        Ub_v + k * 40, Apro, Bpro, msg);
            node_update_kernel<<<1250, 256, 0, stream>>>(cur, msg, Mw_v + k * 3200, Mb_v + k * 40, nxt[k]);
            cur = nxt[k];
        }
    }

    // ---- set2set pair ----
    hipMemsetAsync(q_u, 0, 640000 * sizeof(float), stream);
    hipMemsetAsync(hh, 0, 640000 * sizeof(float), stream);   // hh + cc contiguous
    for (int stp = 0; stp < 2; ++stp) {
        s2s_gates_kernel<<<625, 256, 0, stream>>>(q_u, hh, lsWih, lsWhh, lsbih, lsbhh, gT);
        s2s_update_kernel<<<32, 256, 0, stream>>>(gT, nodes_u, hA_u, hh, cc, q_u);
    }
    hipMemsetAsync(q_v, 0, 640000 * sizeof(float), stream);
    hipMemsetAsync(hh, 0, 640000 * sizeof(float), stream);
    for (int stp = 0; stp < 2; ++stp) {
        s2s_gates_kernel<<<625, 256, 0, stream>>>(q_v, hh, lvWih, lvWhh, lvbih, lvbhh, gT);
        s2s_update_kernel<<<32, 256, 0, stream>>>(gT, nodes_v, hA_v, hh, cc, q_v);
    }

    // ---- bf16 casts ----
    cast_t_kernel<<<2500, 256, 0, stream>>>(q_u, guT);
    cast_t_kernel<<<2500, 256, 0, stream>>>(q_v, gvT);
    cast_pad_kernel<<<3000, 256, 0, stream>>>(q_u, gub);
    cast_pad_kernel<<<3000, 256, 0, stream>>>(q_v, gvb);

    // ---- fused interaction + after-features (barrier-free, plain stores) ----
    hipMemsetAsync(uafT, 0, 1280000 * sizeof(float), stream);   // uafT + vafT contiguous
    fused_kernel<<<dim3(125, 8), 256, 0, stream>>>(gub, gvb, gvT, inter, uafT);      // I + u_afterT
    fused_kernel<<<dim3(125, 8), 256, 0, stream>>>(gvb, gub, guT, nullptr, vafT);    // I^T recompute + v_afterT

    // ---- pools ----
    hipMemsetAsync(pq_u, 0, 640 * sizeof(float), stream);   // pq+ph+pc contiguous
    for (int stp = 0; stp < 2; ++stp) {
        gates_pool_kernel<<<640, 64, 0, stream>>>(gsWih, gsWhh, gsbih, gsbhh, pq_u, ph_u, pgts);
        pool_point_kernel<<<1, 256, 0, stream>>>(pgts, ph_u, pc_u, pq_u);
        pool_scores_kernel<<<32, 256, 0, stream>>>(uafT, q_u, ph_u, scores, pmax);
        pool_softmax_kernel<<<1, 256, 0, stream>>>(scores, pmax, pden);
        pool_r_kernel<<<160, 256, 0, stream>>>(uafT, q_u, scores, pden, pq_u);
    }
    hipMemsetAsync(pq_v, 0, 640 * sizeof(float), stream);
    for (int stp = 0; stp < 2; ++stp) {
        gates_pool_kernel<<<640, 64, 0, stream>>>(gvWih, gvWhh, gvbih, gvbhh, pq_v, ph_v, pgts);
        pool_point_kernel<<<1, 256, 0, stream>>>(pgts, ph_v, pc_v, pq_v);
        pool_scores_kernel<<<32, 256, 0, stream>>>(vafT, q_v, ph_v, scores, pmax);
        pool_softmax_kernel<<<1, 256, 0, stream>>>(scores, pmax, pden);
        pool_r_kernel<<<160, 256, 0, stream>>>(vafT, q_v, scores, pden, pq_v);
    }

    // ---- final MLP ----
    concat_kernel<<<1, 640, 0, stream>>>(pq_u, pq_v, mx0);
    gemv_kernel<<<360, 64, 0, stream>>>(w1, b1, mx0, mx1, 640, 1);
    gemv_kernel<<<200, 64, 0, stream>>>(w2, b2, mx1, mx2, 360, 1);
    gemv_kernel<<<120, 64, 0, stream>>>(w3, b3, mx2, mx3, 200, 1);
    gemv_kernel<<<1, 64, 0, stream>>>(w4, b4, mx3, out, 120, 0);
}

// Round 9
// 1002.616 us; speedup vs baseline: 1.2716x; 1.0403x over previous
//
#include <hip/hip_runtime.h>
#include <cstdint>
#include <cstddef>

#define NN 8000
#define NE 128000
#define NDv 40
#define EDv 10

typedef __attribute__((ext_vector_type(8))) short short8v;
typedef __attribute__((ext_vector_type(4))) float f32x4;

__device__ __forceinline__ float rcp_fast(float x) { return __builtin_amdgcn_rcpf(x); }
__device__ __forceinline__ float sigm(float x) { return rcp_fast(1.f + __expf(-x)); }
__device__ __forceinline__ float ftanh(float x) {
    float e = __expf(2.f * x);
    return 1.f - 2.f * rcp_fast(e + 1.f);
}
__device__ __forceinline__ short f2bf(float x) {   // RNE f32 -> bf16
    unsigned u = __builtin_bit_cast(unsigned, x);
    u += 0x7fffu + ((u >> 16) & 1u);
    return (short)(u >> 16);
}
__device__ __forceinline__ float wsum(float v) {
    for (int o = 32; o; o >>= 1) v += __shfl_down(v, o);
    return v;
}
__device__ __forceinline__ float wmax(float v) {
    for (int o = 32; o; o >>= 1) v = fmaxf(v, __shfl_down(v, o));
    return v;
}

// ---------------- CSR build (per graph, edge index is static) ----------------

__global__ __launch_bounds__(256) void csr_deg_kernel(const int* __restrict__ ei, int* __restrict__ deg) {
    int e = blockIdx.x * 256 + threadIdx.x;
    if (e < NE) atomicAdd(&deg[ei[e]], 1);
}

__global__ __launch_bounds__(64) void csr_scan_kernel(const int* __restrict__ deg, int* __restrict__ off,
                                                      int* __restrict__ woff) {
    int l = threadIdx.x;
    int base = l * 125;
    int s = 0;
    for (int i = 0; i < 125; ++i) s += deg[base + i];
    int pre = s;
    for (int o = 1; o < 64; o <<= 1) { int t = __shfl_up(pre, o); if (l >= o) pre += t; }
    pre -= s;   // exclusive prefix
    int run = pre;
    for (int i = 0; i < 125; ++i) {
        off[base + i] = run; woff[base + i] = run;
        run += deg[base + i];
    }
    if (l == 63) off[NN] = run;
}

// store DESTINATION node id per CSR slot (not edge id)
__global__ __launch_bounds__(256) void csr_fill_kernel(const int* __restrict__ ei, int* __restrict__ woff,
                                                       int* __restrict__ dlist) {
    int e = blockIdx.x * 256 + threadIdx.x;
    if (e < NE) { int p = atomicAdd(&woff[ei[e]], 1); dlist[p] = ei[NE + e]; }
}

// sef[n,k] = sum_{e: src=n} ef[e,k]   (round-independent, once per graph)
__global__ __launch_bounds__(256) void sef_kernel(const int* __restrict__ ei, const float* __restrict__ ef,
                                                  float* __restrict__ sef) {
    int t = blockIdx.x * 256 + threadIdx.x;   // exactly NE*EDv
    int e = t / EDv, k = t % EDv;
    atomicAdd(&sef[ei[e] * EDv + k], ef[t]);
}

// ---------------- message passing ----------------

__global__ __launch_bounds__(256) void node_proj_kernel(const float* __restrict__ h, const float* __restrict__ Uw,
                                                        float* __restrict__ A, float* __restrict__ B) {
    __shared__ float W[40][81];   // Uw[i][0:80], 81-pad -> conflict-free strided reads
    int tid = threadIdx.x;
    for (int s = tid; s < 3200; s += 256) W[s / 80][s % 80] = Uw[(s / 80) * 90 + (s % 80)];
    __syncthreads();
    int t = blockIdx.x * 256 + tid;   // exactly 8000*40
    int n = t / NDv, i = t % NDv;
    float hreg[40];
    const float* hr = h + n * NDv;
#pragma unroll
    for (int k4 = 0; k4 < 10; ++k4) {
        float4 v = *reinterpret_cast<const float4*>(hr + k4 * 4);
        hreg[k4 * 4 + 0] = v.x; hreg[k4 * 4 + 1] = v.y; hreg[k4 * 4 + 2] = v.z; hreg[k4 * 4 + 3] = v.w;
    }
    float a = 0.f, b = 0.f;
#pragma unroll
    for (int k = 0; k < NDv; ++k) { a += W[i][k] * hreg[k]; b += W[i][40 + k] * hreg[k]; }
    A[t] = a; B[t] = b;
}

// msg[n,i] = deg*(A[n,i]+Ub[i]) + Uw[i,80:90]·sef[n] + sum_p B[dlist[p],i]
__global__ __launch_bounds__(256) void msg_gather_kernel(const int* __restrict__ off, const int* __restrict__ dlist,
                                                         const float* __restrict__ sef,
                                                         const float* __restrict__ Uw, const float* __restrict__ Ub,
                                                         const float* __restrict__ A, const float* __restrict__ B,
                                                         float* __restrict__ msg) {
    int t = blockIdx.x * 256 + threadIdx.x;   // exactly 8000*40
    int n = t / NDv, i = t % NDv;
    const float* we = Uw + i * 90 + 80;
    const float* se = sef + n * EDv;
    int p0 = off[n], p1 = off[n + 1];
    float acc = (float)(p1 - p0) * (A[t] + Ub[i]);
#pragma unroll
    for (int k = 0; k < EDv; ++k) acc += we[k] * se[k];
    for (int p = p0; p < p1; ++p) acc += B[dlist[p] * NDv + i];
    msg[t] = acc;
}

__global__ __launch_bounds__(256) void node_update_kernel(const float* __restrict__ h, const float* __restrict__ msg,
                                                          const float* __restrict__ Mw, const float* __restrict__ Mb,
                                                          float* __restrict__ hout) {
    __shared__ float W[40][81];   // Mw[i][0:80]
    int tid = threadIdx.x;
    for (int s = tid; s < 3200; s += 256) W[s / 80][s % 80] = Mw[s];
    __syncthreads();
    int t = blockIdx.x * 256 + tid;   // exactly 8000*40
    int n = t / NDv, i = t % NDv;
    const float* hr = h + n * NDv;
    const float* mr = msg + n * NDv;
    float acc = Mb[i];
#pragma unroll
    for (int k = 0; k < NDv; ++k) acc += W[i][k] * hr[k];
#pragma unroll
    for (int k = 0; k < NDv; ++k) acc += W[i][40 + k] * mr[k];
    hout[t] = fmaxf(acc, 0.f);
}

// ---------------- set2set (pair, per-node LSTM h_d=40) ----------------

__global__ __launch_bounds__(256) void s2s_gates_kernel(const float* __restrict__ q, const float* __restrict__ hh,
                                                        const float* __restrict__ Wih, const float* __restrict__ Whh,
                                                        const float* __restrict__ bih, const float* __restrict__ bhh,
                                                        float* __restrict__ gatesT) {
    int t = blockIdx.x * 256 + threadIdx.x;   // exactly 8000*20
    int n = t % NN;
    int jg = t / NN;
    float qr[80];
#pragma unroll
    for (int k4 = 0; k4 < 20; ++k4) {
        float4 v = *reinterpret_cast<const float4*>(q + n * 80 + k4 * 4);
        qr[k4 * 4 + 0] = v.x; qr[k4 * 4 + 1] = v.y; qr[k4 * 4 + 2] = v.z; qr[k4 * 4 + 3] = v.w;
    }
    float hr[40];
#pragma unroll
    for (int k4 = 0; k4 < 10; ++k4) {
        float4 v = *reinterpret_cast<const float4*>(hh + n * 40 + k4 * 4);
        hr[k4 * 4 + 0] = v.x; hr[k4 * 4 + 1] = v.y; hr[k4 * 4 + 2] = v.z; hr[k4 * 4 + 3] = v.w;
    }
#pragma unroll
    for (int jj = 0; jj < 8; ++jj) {
        int j = jg * 8 + jj;
        const float* wi = Wih + j * 80;
        const float* wh = Whh + j * 40;
        float acc = bih[j] + bhh[j];
#pragma unroll
        for (int k = 0; k < 80; ++k) acc += wi[k] * qr[k];
#pragma unroll
        for (int k = 0; k < 40; ++k) acc += wh[k] * hr[k];
        gatesT[j * NN + n] = acc;
    }
}

__global__ __launch_bounds__(256) void s2s_update_kernel(const float* __restrict__ gatesT,
                                                         const float* __restrict__ h0, const float* __restrict__ ht,
                                                         float* __restrict__ hh, float* __restrict__ cc,
                                                         float* __restrict__ q) {
    int n = blockIdx.x * 256 + threadIdx.x;
    if (n >= NN) return;
    float hreg[40];
    float e0 = 0.f, e1 = 0.f;
#pragma unroll
    for (int i = 0; i < 40; ++i) {
        float gi = gatesT[i * NN + n];
        float gf = gatesT[(40 + i) * NN + n];
        float gg = gatesT[(80 + i) * NN + n];
        float go = gatesT[(120 + i) * NN + n];
        float cn = sigm(gf) * cc[n * 40 + i] + sigm(gi) * ftanh(gg);
        cc[n * 40 + i] = cn;
        float hn = sigm(go) * ftanh(cn);
        hreg[i] = hn;
        e0 += h0[n * 40 + i] * hn;
        e1 += ht[n * 40 + i] * hn;
    }
    float m = fmaxf(e0, e1);
    float p0 = __expf(e0 - m), p1 = __expf(e1 - m);
    float inv = rcp_fast(p0 + p1);
    float a0 = p0 * inv, a1 = p1 * inv;
#pragma unroll
    for (int i = 0; i < 40; ++i) {
        hh[n * 40 + i] = hreg[i];
        q[n * 80 + i] = hreg[i];
        q[n * 80 + 40 + i] = a0 * h0[n * 40 + i] + a1 * ht[n * 40 + i];
    }
}

// ---------------- bf16 casts (u and v via blockIdx.y) ----------------

__global__ __launch_bounds__(256) void cast_pad_kernel(const float* __restrict__ gu, const float* __restrict__ gv,
                                                       short* __restrict__ ou, short* __restrict__ ov) {
    int t = blockIdx.x * 256 + threadIdx.x;   // exactly 8000*96
    const float* g = blockIdx.y ? gv : gu;
    short* o = blockIdx.y ? ov : ou;
    int m = t / 96, k = t % 96;
    o[t] = (k < 80) ? f2bf(g[m * 80 + k]) : (short)0;
}

__global__ __launch_bounds__(256) void cast_t_kernel(const float* __restrict__ gu, const float* __restrict__ gv,
                                                     short* __restrict__ ou, short* __restrict__ ov) {
    int t = blockIdx.x * 256 + threadIdx.x;   // exactly 80*8000
    const float* g = blockIdx.y ? gv : gu;
    short* o = blockIdx.y ? ov : ou;
    int m = t % NN, f = t / NN;
    o[t] = f2bf(g[m * 80 + f]);
}

// ---------------- fused interaction + after-feature (barrier-free, wave-private P) ----------------
// blockIdx.z = 0: I = gu@gv^T (stored) + u_afterT;  z = 1: I^T recomputed + v_afterT.
// Each wave owns 16 X-rows. Per 64-wide Y-chunk:
//   accI = X(16 rows) @ Y(64 rows)^T -> [store z==0] -> P=tanh bf16 (wave-private LDS) -> acc += P @ YT
// grid (125 x-tiles, 8 y-chunks, 2 variants) = 2000 blocks (~31 waves/CU).

__global__ __launch_bounds__(256) void fused_kernel(const short* __restrict__ gub, const short* __restrict__ gvb,
                                                    const short* __restrict__ guT, const short* __restrict__ gvT,
                                                    float* __restrict__ inter,
                                                    float* __restrict__ uafT, float* __restrict__ vafT) {
    __shared__ short P[4][16][72];   // per-wave [row][col], 144B row stride
    const short* Xb; const short* Yb; const short* YT; float* Iout; float* afT;
    if (blockIdx.z == 0) { Xb = gub; Yb = gvb; YT = gvT; Iout = inter; afT = uafT; }
    else                 { Xb = gvb; Yb = gub; YT = guT; Iout = nullptr; afT = vafT; }
    int tid = threadIdx.x;
    int w = tid >> 6, l = tid & 63;
    int lrow = l & 15, lk = l >> 4;
    int x0 = blockIdx.x * 64;
    int it0 = (125 * blockIdx.y) >> 3;
    int it1 = (125 * (blockIdx.y + 1)) >> 3;
    short8v a_x[3];
    const short* arow = Xb + (size_t)(x0 + w * 16 + lrow) * 96 + lk * 8;
#pragma unroll
    for (int ks = 0; ks < 3; ++ks) a_x[ks] = *reinterpret_cast<const short8v*>(arow + ks * 32);
    f32x4 acc[5] = {};
    for (int it = it0; it < it1; ++it) {
        int k0 = it * 64;
        f32x4 accI[4] = {};
#pragma unroll
        for (int ks = 0; ks < 3; ++ks) {
#pragma unroll
            for (int nt = 0; nt < 4; ++nt) {
                short8v b = *reinterpret_cast<const short8v*>(Yb + (size_t)(k0 + nt * 16 + lrow) * 96 + ks * 32 + lk * 8);
                accI[nt] = __builtin_amdgcn_mfma_f32_16x16x32_bf16(a_x[ks], b, accI[nt], 0, 0, 0);
            }
        }
#pragma unroll
        for (int nt = 0; nt < 4; ++nt)
#pragma unroll
            for (int r = 0; r < 4; ++r) {
                float v = accI[nt][r];
                if (Iout)
                    Iout[(size_t)(x0 + w * 16 + lk * 4 + r) * NN + (k0 + nt * 16 + lrow)] = v;
                P[w][lk * 4 + r][nt * 16 + lrow] = f2bf(ftanh(v));
            }
        // wave-private LDS: same-wave write->read is in-order, no barrier needed
#pragma unroll
        for (int ks2 = 0; ks2 < 2; ++ks2) {
            short8v ap = *reinterpret_cast<const short8v*>(&P[w][lrow][ks2 * 32 + lk * 8]);
#pragma unroll
            for (int ft = 0; ft < 5; ++ft) {
                short8v b = *reinterpret_cast<const short8v*>(YT + (size_t)(ft * 16 + lrow) * NN + k0 + ks2 * 32 + lk * 8);
                acc[ft] = __builtin_amdgcn_mfma_f32_16x16x32_bf16(ap, b, acc[ft], 0, 0, 0);
            }
        }
    }
    int xout = x0 + w * 16 + lk * 4;
#pragma unroll
    for (int ft = 0; ft < 5; ++ft)
#pragma unroll
        for (int r = 0; r < 4; ++r)
            atomicAdd(&afT[(size_t)(ft * 16 + lrow) * NN + xout + r], acc[ft][r]);
}

// ---------------- set2set pool (batch 1, h_d=160) ----------------

__global__ __launch_bounds__(64) void gates_pool_kernel(const float* __restrict__ Wih, const float* __restrict__ Whh,
                                                        const float* __restrict__ bih, const float* __restrict__ bhh,
                                                        const float* __restrict__ q, const float* __restrict__ h,
                                                        float* __restrict__ gts) {
    int j = blockIdx.x;
    int lane = threadIdx.x;
    const float* wi = Wih + j * 320;
    const float* wh = Whh + j * 160;
    float p = 0.f;
#pragma unroll
    for (int k4 = 0; k4 < 5; ++k4) { int k = lane + k4 * 64; p += wi[k] * q[k]; }
#pragma unroll
    for (int k4 = 0; k4 < 3; ++k4) { int k = lane + k4 * 64; if (k < 160) p += wh[k] * h[k]; }
    p = wsum(p);
    if (lane == 0) gts[j] = p + bih[j] + bhh[j];
}

__global__ __launch_bounds__(256) void pool_point_kernel(const float* __restrict__ gts, float* __restrict__ h,
                                                         float* __restrict__ c, float* __restrict__ q) {
    int tid = threadIdx.x;
    if (tid < 160) {
        float cn = sigm(gts[160 + tid]) * c[tid] + sigm(gts[tid]) * ftanh(gts[320 + tid]);
        c[tid] = cn;
        float hn = sigm(gts[480 + tid]) * ftanh(cn);
        h[tid] = hn;
        q[tid] = hn;   // q_star[0:160] = h
    }
}

__global__ __launch_bounds__(256) void pool_scores_kernel(const float* __restrict__ afT, const float* __restrict__ g,
                                                          const float* __restrict__ h, float* __restrict__ scores,
                                                          float* __restrict__ pmax) {
    int tid = threadIdx.x;
    int n = blockIdx.x * 256 + tid;
    float s = -3.4e38f;
    if (n < NN) {
        float acc = 0.f;
#pragma unroll 8
        for (int k = 0; k < 80; ++k) acc += afT[k * NN + n] * h[k];
        const float* gr = g + n * 80;
#pragma unroll 8
        for (int k = 0; k < 80; ++k) acc += gr[k] * h[80 + k];
        scores[n] = acc;
        s = acc;
    }
    __shared__ float red[4];
    float m = wmax(s);
    if ((tid & 63) == 0) red[tid >> 6] = m;
    __syncthreads();
    if (tid == 0) pmax[blockIdx.x] = fmaxf(fmaxf(red[0], red[1]), fmaxf(red[2], red[3]));
}

__global__ __launch_bounds__(256) void pool_softmax_kernel(float* __restrict__ scores, const float* __restrict__ pmax,
                                                           float* __restrict__ denom) {
    int tid = threadIdx.x;
    __shared__ float sm;
    __shared__ float red[4];
    float m = (tid < 32) ? pmax[tid] : -3.4e38f;
    m = wmax(m);
    if (tid == 0) sm = m;
    __syncthreads();
    float mm = sm;
    float lsum = 0.f;
    for (int n = tid; n < NN; n += 256) {
        float e = __expf(scores[n] - mm);
        scores[n] = e;
        lsum += e;
    }
    float w = wsum(lsum);
    if ((tid & 63) == 0) red[tid >> 6] = w;
    __syncthreads();
    if (tid == 0) denom[0] = red[0] + red[1] + red[2] + red[3];
}

__global__ __launch_bounds__(256) void pool_r_kernel(const float* __restrict__ afT, const float* __restrict__ g,
                                                     const float* __restrict__ scores, const float* __restrict__ denom,
                                                     float* __restrict__ q) {
    int f = blockIdx.x;   // 0..159
    int tid = threadIdx.x;
    float acc = 0.f;
    if (f < 80) {
        const float* x = afT + (size_t)f * NN;
        for (int n = tid; n < NN; n += 256) acc += scores[n] * x[n];
    } else {
        const float* x = g + (f - 80);
        for (int n = tid; n < NN; n += 256) acc += scores[n] * x[(size_t)n * 80];
    }
    float w = wsum(acc);
    __shared__ float red[4];
    if ((tid & 63) == 0) red[tid >> 6] = w;
    __syncthreads();
    if (tid == 0) q[160 + f] = (red[0] + red[1] + red[2] + red[3]) * rcp_fast(denom[0]);
}

// ---------------- final MLP (parallel per-row GEMVs) ----------------

__global__ __launch_bounds__(640) void concat_kernel(const float* __restrict__ cu, const float* __restrict__ cv,
                                                     float* __restrict__ x0) {
    int tid = threadIdx.x;
    x0[tid] = (tid < 320) ? cu[tid] : cv[tid - 320];
}

__global__ __launch_bounds__(64) void gemv_kernel(const float* __restrict__ W, const float* __restrict__ b,
                                                  const float* __restrict__ x, float* __restrict__ y,
                                                  int K, int relu) {
    int j = blockIdx.x;
    int lane = threadIdx.x;
    const float* w = W + (size_t)j * K;
    float p = 0.f;
    for (int k = lane; k < K; k += 64) p += w[k] * x[k];
    p = wsum(p);
    if (lane == 0) {
        p += b[j];
        y[j] = relu ? fmaxf(p, 0.f) : p;
    }
}

// ---------------- launch ----------------

extern "C" void kernel_launch(void* const* d_in, const int* in_sizes, int n_in,
                              void* d_out, int out_size, void* d_ws, size_t ws_size,
                              hipStream_t stream) {
    const float* nodes_u = (const float*)d_in[0];
    const int* ei_u = (const int*)d_in[1];
    const float* ef_u = (const float*)d_in[2];
    const float* nodes_v = (const float*)d_in[3];
    const int* ei_v = (const int*)d_in[4];
    const float* ef_v = (const float*)d_in[5];
    const float* Uw_u = (const float*)d_in[6];
    const float* Ub_u = (const float*)d_in[7];
    const float* Mw_u = (const float*)d_in[8];
    const float* Mb_u = (const float*)d_in[9];
    const float* Uw_v = (const float*)d_in[10];
    const float* Ub_v = (const float*)d_in[11];
    const float* Mw_v = (const float*)d_in[12];
    const float* Mb_v = (const float*)d_in[13];
    const float* lsWih = (const float*)d_in[14];
    const float* lsWhh = (const float*)d_in[15];
    const float* lsbih = (const float*)d_in[16];
    const float* lsbhh = (const float*)d_in[17];
    const float* lvWih = (const float*)d_in[18];
    const float* lvWhh = (const float*)d_in[19];
    const float* lvbih = (const float*)d_in[20];
    const float* lvbhh = (const float*)d_in[21];
    const float* gsWih = (const float*)d_in[22];
    const float* gsWhh = (const float*)d_in[23];
    const float* gsbih = (const float*)d_in[24];
    const float* gsbhh = (const float*)d_in[25];
    const float* gvWih = (const float*)d_in[26];
    const float* gvWhh = (const float*)d_in[27];
    const float* gvbih = (const float*)d_in[28];
    const float* gvbhh = (const float*)d_in[29];
    const float* w1 = (const float*)d_in[30];
    const float* b1 = (const float*)d_in[31];
    const float* w2 = (const float*)d_in[32];
    const float* b2 = (const float*)d_in[33];
    const float* w3 = (const float*)d_in[34];
    const float* b3 = (const float*)d_in[35];
    const float* w4 = (const float*)d_in[36];
    const float* b4 = (const float*)d_in[37];

    float* ws = (float*)d_ws;
    float* hA_u = ws + 0;
    float* hB_u = ws + 320000;
    float* hA_v = ws + 640000;
    float* hB_v = ws + 960000;
    float* msg  = ws + 1280000;
    float* Apro = ws + 1600000;
    float* Bpro = ws + 1920000;
    float* q_u  = ws + 2240000;   // gu [8000,80]
    float* q_v  = ws + 2880000;   // gv [8000,80]
    float* hh   = ws + 3520000;   // u-graph LSTM state
    float* cc   = ws + 3840000;
    float* gT   = ws + 4160000;   // gates transposed [160][8000] (s2s phase only)
    float* sef_u = ws + 4160000;  // [8000][10] — dead before s2s starts
    float* sef_v = ws + 4240000;  // [8000][10]
    float* uafT = ws + 5440000;   // [80][8000]
    float* vafT = ws + 6080000;   // [80][8000]
    float* scores = ws + 6720000;
    float* pmax = ws + 6728000;
    float* pden = ws + 6728032;
    float* pq_u = ws + 6728040;
    float* ph_u = ws + 6728360;
    float* pc_u = ws + 6728520;
    float* pq_v = ws + 6728680;
    float* ph_v = ws + 6729000;
    float* pc_v = ws + 6729160;
    float* pgts = ws + 6729320;   // 640
    float* mx0  = ws + 6729960;   // 640
    float* mx1  = ws + 6730600;   // 360
    float* mx2  = ws + 6730960;   // 200
    float* mx3  = ws + 6731160;   // 120
    int* ioff_u   = (int*)(ws + 6731280);   // 8001 (pad 8064)
    int* idlist_u = (int*)(ws + 6739344);   // 128000
    int* ioff_v   = (int*)(ws + 6867344);   // 8064
    int* idlist_v = (int*)(ws + 6875408);   // 128000
    int* iwoff    = (int*)(ws + 7003408);   // 8064
    int* ideg     = (int*)(ws + 7011472);   // 8064
    float* hh_v = ws + 7019536;   // v-graph LSTM state [320000]
    float* cc_v = ws + 7339536;   // [320000]

    // bf16 buffers reuse the (dead by then) message-passing region
    short* guT = (short*)(ws + 0);        // [80][8000]
    short* gvT = (short*)(ws + 320000);   // [80][8000]
    short* gub = (short*)(ws + 640000);   // [8000][96]
    short* gvb = (short*)(ws + 1024000);  // [8000][96]

    float* out = (float*)d_out;
    float* inter = out + 1;

    // ---- CSR + edge-feature sums: u ----
    hipMemsetAsync(ideg, 0, NN * sizeof(int), stream);
    hipMemsetAsync(sef_u, 0, NN * EDv * sizeof(float), stream);
    csr_deg_kernel<<<500, 256, 0, stream>>>(ei_u, ideg);
    csr_scan_kernel<<<1, 64, 0, stream>>>(ideg, ioff_u, iwoff);
    csr_fill_kernel<<<500, 256, 0, stream>>>(ei_u, iwoff, idlist_u);
    sef_kernel<<<5000, 256, 0, stream>>>(ei_u, ef_u, sef_u);
    // ---- CSR + edge-feature sums: v ----
    hipMemsetAsync(ideg, 0, NN * sizeof(int), stream);
    hipMemsetAsync(sef_v, 0, NN * EDv * sizeof(float), stream);
    csr_deg_kernel<<<500, 256, 0, stream>>>(ei_v, ideg);
    csr_scan_kernel<<<1, 64, 0, stream>>>(ideg, ioff_v, iwoff);
    csr_fill_kernel<<<500, 256, 0, stream>>>(ei_v, iwoff, idlist_v);
    sef_kernel<<<5000, 256, 0, stream>>>(ei_v, ef_v, sef_v);

    // ---- message passing: u ----
    {
        const float* cur = nodes_u;
        float* nxt[3] = {hA_u, hB_u, hA_u};
        for (int k = 0; k < 3; ++k) {
            node_proj_kernel<<<1250, 256, 0, stream>>>(cur, Uw_u + k * 3600, Apro, Bpro);
            msg_gather_kernel<<<1250, 256, 0, stream>>>(ioff_u, idlist_u, sef_u, Uw_u + k * 3600,
                                                        Ub_u + k * 40, Apro, Bpro, msg);
            node_update_kernel<<<1250, 256, 0, stream>>>(cur, msg, Mw_u + k * 3200, Mb_u + k * 40, nxt[k]);
            cur = nxt[k];
        }
    }
    // ---- message passing: v ----
    {
        const float* cur = nodes_v;
        float* nxt[3] = {hA_v, hB_v, hA_v};
        for (int k = 0; k < 3; ++k) {
            node_proj_kernel<<<1250, 256, 0, stream>>>(cur, Uw_v + k * 3600, Apro, Bpro);
            msg_gather_kernel<<<1250, 256, 0, stream>>>(ioff_v, idlist_v, sef_v, Uw_v + k * 3600,
                                                        Ub_v + k * 40, Apro, Bpro, msg);
            node_update_kernel<<<1250, 256, 0, stream>>>(cur, msg, Mw_v + k * 3200, Mb_v + k * 40, nxt[k]);
            cur = nxt[k];
        }
    }

    // ---- set2set pair (q_u,q_v,hh,cc contiguous -> one memset; v uses hh_v/cc_v) ----
    hipMemsetAsync(q_u, 0, 1920000 * sizeof(float), stream);     // q_u,q_v,hh,cc
    hipMemsetAsync(hh_v, 0, 640000 * sizeof(float), stream);     // hh_v,cc_v
    for (int stp = 0; stp < 2; ++stp) {
        s2s_gates_kernel<<<625, 256, 0, stream>>>(q_u, hh, lsWih, lsWhh, lsbih, lsbhh, gT);
        s2s_update_kernel<<<32, 256, 0, stream>>>(gT, nodes_u, hA_u, hh, cc, q_u);
    }
    for (int stp = 0; stp < 2; ++stp) {
        s2s_gates_kernel<<<625, 256, 0, stream>>>(q_v, hh_v, lvWih, lvWhh, lvbih, lvbhh, gT);
        s2s_update_kernel<<<32, 256, 0, stream>>>(gT, nodes_v, hA_v, hh_v, cc_v, q_v);
    }

    // ---- bf16 casts (u+v in one launch each) ----
    cast_t_kernel<<<dim3(2500, 2), 256, 0, stream>>>(q_u, q_v, guT, gvT);
    cast_pad_kernel<<<dim3(3000, 2), 256, 0, stream>>>(q_u, q_v, gub, gvb);

    // ---- fused interaction + after-features (both variants, one launch) ----
    hipMemsetAsync(uafT, 0, 1280000 * sizeof(float), stream);   // uafT + vafT contiguous
    fused_kernel<<<dim3(125, 8, 2), 256, 0, stream>>>(gub, gvb, guT, gvT, inter, uafT, vafT);

    // ---- pools ----
    hipMemsetAsync(pq_u, 0, 1280 * sizeof(float), stream);   // pq_u..pc_v contiguous
    for (int stp = 0; stp < 2; ++stp) {
        gates_pool_kernel<<<640, 64, 0, stream>>>(gsWih, gsWhh, gsbih, gsbhh, pq_u, ph_u, pgts);
        pool_point_kernel<<<1, 256, 0, stream>>>(pgts, ph_u, pc_u, pq_u);
        pool_scores_kernel<<<32, 256, 0, stream>>>(uafT, q_u, ph_u, scores, pmax);
        pool_softmax_kernel<<<1, 256, 0, stream>>>(scores, pmax, pden);
        pool_r_kernel<<<160, 256, 0, stream>>>(uafT, q_u, scores, pden, pq_u);
    }
    for (int stp = 0; stp < 2; ++stp) {
        gates_pool_kernel<<<640, 64, 0, stream>>>(gvWih, gvWhh, gvbih, gvbhh, pq_v, ph_v, pgts);
        pool_point_kernel<<<1, 256, 0, stream>>>(pgts, ph_v, pc_v, pq_v);
        pool_scores_kernel<<<32, 256, 0, stream>>>(vafT, q_v, ph_v, scores, pmax);
        pool_softmax_kernel<<<1, 256, 0, stream>>>(scores, pmax, pden);
        pool_r_kernel<<<160, 256, 0, stream>>>(vafT, q_v, scores, pden, pq_v);
    }

    // ---- final MLP ----
    concat_kernel<<<1, 640, 0, stream>>>(pq_u, pq_v, mx0);
    gemv_kernel<<<360, 64, 0, stream>>>(w1, b1, mx0, mx1, 640, 1);
    gemv_kernel<<<200, 64, 0, stream>>>(w2, b2, mx1, mx2, 360, 1);
    gemv_kernel<<<120, 64, 0, stream>>>(w3, b3, mx2, mx3, 200, 1);
    gemv_kernel<<<1, 64, 0, stream>>>(w4, b4, mx3, out, 120, 0);
}

// Round 10
// 978.359 us; speedup vs baseline: 1.3031x; 1.0248x over previous
//
#include <hip/hip_runtime.h>
#include <cstdint>
#include <cstddef>

#define NN 8000
#define NE 128000
#define NDv 40
#define EDv 10

typedef __attribute__((ext_vector_type(8))) short short8v;
typedef __attribute__((ext_vector_type(4))) float f32x4;

__device__ __forceinline__ float rcp_fast(float x) { return __builtin_amdgcn_rcpf(x); }
__device__ __forceinline__ float sigm(float x) { return rcp_fast(1.f + __expf(-x)); }
__device__ __forceinline__ float ftanh(float x) {
    float e = __expf(2.f * x);
    return 1.f - 2.f * rcp_fast(e + 1.f);
}
__device__ __forceinline__ short f2bf(float x) {   // RNE f32 -> bf16
    unsigned u = __builtin_bit_cast(unsigned, x);
    u += 0x7fffu + ((u >> 16) & 1u);
    return (short)(u >> 16);
}
__device__ __forceinline__ float wsum(float v) {
    for (int o = 32; o; o >>= 1) v += __shfl_down(v, o);
    return v;
}
__device__ __forceinline__ float wmax(float v) {
    for (int o = 32; o; o >>= 1) v = fmaxf(v, __shfl_down(v, o));
    return v;
}

// ---------------- CSR build (per graph, edge index is static) ----------------

__global__ __launch_bounds__(256) void csr_deg_kernel(const int* __restrict__ ei, int* __restrict__ deg) {
    int e = blockIdx.x * 256 + threadIdx.x;
    if (e < NE) atomicAdd(&deg[ei[e]], 1);
}

__global__ __launch_bounds__(64) void csr_scan_kernel(const int* __restrict__ deg, int* __restrict__ off,
                                                      int* __restrict__ woff) {
    int l = threadIdx.x;
    int base = l * 125;
    int s = 0;
    for (int i = 0; i < 125; ++i) s += deg[base + i];
    int pre = s;
    for (int o = 1; o < 64; o <<= 1) { int t = __shfl_up(pre, o); if (l >= o) pre += t; }
    pre -= s;   // exclusive prefix
    int run = pre;
    for (int i = 0; i < 125; ++i) {
        off[base + i] = run; woff[base + i] = run;
        run += deg[base + i];
    }
    if (l == 63) off[NN] = run;
}

// store DESTINATION node id per CSR slot (not edge id)
__global__ __launch_bounds__(256) void csr_fill_kernel(const int* __restrict__ ei, int* __restrict__ woff,
                                                       int* __restrict__ dlist) {
    int e = blockIdx.x * 256 + threadIdx.x;
    if (e < NE) { int p = atomicAdd(&woff[ei[e]], 1); dlist[p] = ei[NE + e]; }
}

// sef[n,k] = sum_{e: src=n} ef[e,k]   (round-independent, once per graph)
__global__ __launch_bounds__(256) void sef_kernel(const int* __restrict__ ei, const float* __restrict__ ef,
                                                  float* __restrict__ sef) {
    int t = blockIdx.x * 256 + threadIdx.x;   // exactly NE*EDv
    int e = t / EDv, k = t % EDv;
    atomicAdd(&sef[ei[e] * EDv + k], ef[t]);
}

// ---------------- message passing ----------------

__global__ __launch_bounds__(256) void node_proj_kernel(const float* __restrict__ h, const float* __restrict__ Uw,
                                                        float* __restrict__ A, float* __restrict__ B) {
    __shared__ float W[40][81];   // Uw[i][0:80], 81-pad -> conflict-free strided reads
    int tid = threadIdx.x;
    for (int s = tid; s < 3200; s += 256) W[s / 80][s % 80] = Uw[(s / 80) * 90 + (s % 80)];
    __syncthreads();
    int t = blockIdx.x * 256 + tid;   // exactly 8000*40
    int n = t / NDv, i = t % NDv;
    float hreg[40];
    const float* hr = h + n * NDv;
#pragma unroll
    for (int k4 = 0; k4 < 10; ++k4) {
        float4 v = *reinterpret_cast<const float4*>(hr + k4 * 4);
        hreg[k4 * 4 + 0] = v.x; hreg[k4 * 4 + 1] = v.y; hreg[k4 * 4 + 2] = v.z; hreg[k4 * 4 + 3] = v.w;
    }
    float a = 0.f, b = 0.f;
#pragma unroll
    for (int k = 0; k < NDv; ++k) { a += W[i][k] * hreg[k]; b += W[i][40 + k] * hreg[k]; }
    A[t] = a; B[t] = b;
}

// msg[n,i] = deg*(A[n,i]+Ub[i]) + Uw[i,80:90]·sef[n] + sum_p B[dlist[p],i]
__global__ __launch_bounds__(256) void msg_gather_kernel(const int* __restrict__ off, const int* __restrict__ dlist,
                                                         const float* __restrict__ sef,
                                                         const float* __restrict__ Uw, const float* __restrict__ Ub,
                                                         const float* __restrict__ A, const float* __restrict__ B,
                                                         float* __restrict__ msg) {
    int t = blockIdx.x * 256 + threadIdx.x;   // exactly 8000*40
    int n = t / NDv, i = t % NDv;
    const float* we = Uw + i * 90 + 80;
    const float* se = sef + n * EDv;
    int p0 = off[n], p1 = off[n + 1];
    float acc = (float)(p1 - p0) * (A[t] + Ub[i]);
#pragma unroll
    for (int k = 0; k < EDv; ++k) acc += we[k] * se[k];
    for (int p = p0; p < p1; ++p) acc += B[dlist[p] * NDv + i];
    msg[t] = acc;
}

__global__ __launch_bounds__(256) void node_update_kernel(const float* __restrict__ h, const float* __restrict__ msg,
                                                          const float* __restrict__ Mw, const float* __restrict__ Mb,
                                                          float* __restrict__ hout) {
    __shared__ float W[40][81];   // Mw[i][0:80]
    int tid = threadIdx.x;
    for (int s = tid; s < 3200; s += 256) W[s / 80][s % 80] = Mw[s];
    __syncthreads();
    int t = blockIdx.x * 256 + tid;   // exactly 8000*40
    int n = t / NDv, i = t % NDv;
    const float* hr = h + n * NDv;
    const float* mr = msg + n * NDv;
    float acc = Mb[i];
#pragma unroll
    for (int k = 0; k < NDv; ++k) acc += W[i][k] * hr[k];
#pragma unroll
    for (int k = 0; k < NDv; ++k) acc += W[i][40 + k] * mr[k];
    hout[t] = fmaxf(acc, 0.f);
}

// ---------------- set2set (pair, per-node LSTM h_d=40) ----------------

__global__ __launch_bounds__(256) void s2s_gates_kernel(const float* __restrict__ q, const float* __restrict__ hh,
                                                        const float* __restrict__ Wih, const float* __restrict__ Whh,
                                                        const float* __restrict__ bih, const float* __restrict__ bhh,
                                                        float* __restrict__ gatesT) {
    int t = blockIdx.x * 256 + threadIdx.x;   // exactly 8000*20
    int n = t % NN;
    int jg = t / NN;
    float qr[80];
#pragma unroll
    for (int k4 = 0; k4 < 20; ++k4) {
        float4 v = *reinterpret_cast<const float4*>(q + n * 80 + k4 * 4);
        qr[k4 * 4 + 0] = v.x; qr[k4 * 4 + 1] = v.y; qr[k4 * 4 + 2] = v.z; qr[k4 * 4 + 3] = v.w;
    }
    float hr[40];
#pragma unroll
    for (int k4 = 0; k4 < 10; ++k4) {
        float4 v = *reinterpret_cast<const float4*>(hh + n * 40 + k4 * 4);
        hr[k4 * 4 + 0] = v.x; hr[k4 * 4 + 1] = v.y; hr[k4 * 4 + 2] = v.z; hr[k4 * 4 + 3] = v.w;
    }
#pragma unroll
    for (int jj = 0; jj < 8; ++jj) {
        int j = jg * 8 + jj;
        const float* wi = Wih + j * 80;
        const float* wh = Whh + j * 40;
        float acc = bih[j] + bhh[j];
#pragma unroll
        for (int k = 0; k < 80; ++k) acc += wi[k] * qr[k];
#pragma unroll
        for (int k = 0; k < 40; ++k) acc += wh[k] * hr[k];
        gatesT[j * NN + n] = acc;
    }
}

__global__ __launch_bounds__(256) void s2s_update_kernel(const float* __restrict__ gatesT,
                                                         const float* __restrict__ h0, const float* __restrict__ ht,
                                                         float* __restrict__ hh, float* __restrict__ cc,
                                                         float* __restrict__ q) {
    int n = blockIdx.x * 256 + threadIdx.x;
    if (n >= NN) return;
    float hreg[40];
    float e0 = 0.f, e1 = 0.f;
#pragma unroll
    for (int i = 0; i < 40; ++i) {
        float gi = gatesT[i * NN + n];
        float gf = gatesT[(40 + i) * NN + n];
        float gg = gatesT[(80 + i) * NN + n];
        float go = gatesT[(120 + i) * NN + n];
        float cn = sigm(gf) * cc[n * 40 + i] + sigm(gi) * ftanh(gg);
        cc[n * 40 + i] = cn;
        float hn = sigm(go) * ftanh(cn);
        hreg[i] = hn;
        e0 += h0[n * 40 + i] * hn;
        e1 += ht[n * 40 + i] * hn;
    }
    float m = fmaxf(e0, e1);
    float p0 = __expf(e0 - m), p1 = __expf(e1 - m);
    float inv = rcp_fast(p0 + p1);
    float a0 = p0 * inv, a1 = p1 * inv;
#pragma unroll
    for (int i = 0; i < 40; ++i) {
        hh[n * 40 + i] = hreg[i];
        q[n * 80 + i] = hreg[i];
        q[n * 80 + 40 + i] = a0 * h0[n * 40 + i] + a1 * ht[n * 40 + i];
    }
}

// ---------------- bf16 casts (u and v via blockIdx.y) ----------------

__global__ __launch_bounds__(256) void cast_pad_kernel(const float* __restrict__ gu, const float* __restrict__ gv,
                                                       short* __restrict__ ou, short* __restrict__ ov) {
    int t = blockIdx.x * 256 + threadIdx.x;   // exactly 8000*96
    const float* g = blockIdx.y ? gv : gu;
    short* o = blockIdx.y ? ov : ou;
    int m = t / 96, k = t % 96;
    o[t] = (k < 80) ? f2bf(g[m * 80 + k]) : (short)0;
}

__global__ __launch_bounds__(256) void cast_t_kernel(const float* __restrict__ gu, const float* __restrict__ gv,
                                                     short* __restrict__ ou, short* __restrict__ ov) {
    int t = blockIdx.x * 256 + threadIdx.x;   // exactly 80*8000
    const float* g = blockIdx.y ? gv : gu;
    short* o = blockIdx.y ? ov : ou;
    int m = t % NN, f = t / NN;
    o[t] = f2bf(g[m * 80 + f]);
}

// ---------------- fused interaction + after-feature (barrier-free, SW-pipelined) ----------------
// blockIdx.z = 0: I = gu@gv^T (stored) + u_afterT;  z = 1: I^T recomputed + v_afterT.
// Per iteration, ISSUE ORDER is loads-first / stores-LAST:
//   prefetch next Y-frags -> YT loads -> I-MFMA -> tanh -> LDS (wave-private) -> PV-MFMA -> I stores.
// vmcnt completes in issue order, so waiting on a load never drains the trailing I-stores.

__global__ __launch_bounds__(256, 2) void fused_kernel(const short* __restrict__ gub, const short* __restrict__ gvb,
                                                       const short* __restrict__ guT, const short* __restrict__ gvT,
                                                       float* __restrict__ inter,
                                                       float* __restrict__ uafT, float* __restrict__ vafT) {
    __shared__ short P[4][16][72];   // per-wave [row][col], 144B row stride
    const short* Xb; const short* Yb; const short* YT; float* afT;
    bool storeI = (blockIdx.z == 0);
    if (storeI) { Xb = gub; Yb = gvb; YT = gvT; afT = uafT; }
    else        { Xb = gvb; Yb = gub; YT = guT; afT = vafT; }
    int tid = threadIdx.x;
    int w = tid >> 6, l = tid & 63;
    int lrow = l & 15, lk = l >> 4;
    int x0 = blockIdx.x * 64;
    int it0 = (125 * blockIdx.y) >> 3;
    int it1 = (125 * (blockIdx.y + 1)) >> 3;
    short8v a_x[3];
    const short* arow = Xb + (size_t)(x0 + w * 16 + lrow) * 96 + lk * 8;
#pragma unroll
    for (int ks = 0; ks < 3; ++ks) a_x[ks] = *reinterpret_cast<const short8v*>(arow + ks * 32);
    const short* ybase = Yb + (size_t)lrow * 96 + lk * 8;

    f32x4 acc[5] = {};
    short8v bc[12], bn[12];
#pragma unroll
    for (int i = 0; i < 12; ++i) {
        int ks = i >> 2, nt = i & 3;
        bc[i] = *reinterpret_cast<const short8v*>(ybase + (size_t)(it0 * 64 + nt * 16) * 96 + ks * 32);
    }
    for (int it = it0; it < it1; ++it) {
        int k0 = it * 64;
        if (it + 1 < it1) {
#pragma unroll
            for (int i = 0; i < 12; ++i) {
                int ks = i >> 2, nt = i & 3;
                bn[i] = *reinterpret_cast<const short8v*>(ybase + (size_t)(k0 + 64 + nt * 16) * 96 + ks * 32);
            }
        }
        short8v byt[10];
#pragma unroll
        for (int ks2 = 0; ks2 < 2; ++ks2)
#pragma unroll
            for (int ft = 0; ft < 5; ++ft)
                byt[ks2 * 5 + ft] = *reinterpret_cast<const short8v*>(YT + (size_t)(ft * 16 + lrow) * NN + k0 + ks2 * 32 + lk * 8);
        f32x4 accI[4] = {};
#pragma unroll
        for (int ks = 0; ks < 3; ++ks)
#pragma unroll
            for (int nt = 0; nt < 4; ++nt)
                accI[nt] = __builtin_amdgcn_mfma_f32_16x16x32_bf16(a_x[ks], bc[ks * 4 + nt], accI[nt], 0, 0, 0);
#pragma unroll
        for (int nt = 0; nt < 4; ++nt)
#pragma unroll
            for (int r = 0; r < 4; ++r)
                P[w][lk * 4 + r][nt * 16 + lrow] = f2bf(ftanh(accI[nt][r]));
        // wave-private LDS: same-wave write->read is in-order, no barrier needed
#pragma unroll
        for (int ks2 = 0; ks2 < 2; ++ks2) {
            short8v ap = *reinterpret_cast<const short8v*>(&P[w][lrow][ks2 * 32 + lk * 8]);
#pragma unroll
            for (int ft = 0; ft < 5; ++ft)
                acc[ft] = __builtin_amdgcn_mfma_f32_16x16x32_bf16(ap, byt[ks2 * 5 + ft], acc[ft], 0, 0, 0);
        }
        if (storeI) {
#pragma unroll
            for (int nt = 0; nt < 4; ++nt)
#pragma unroll
                for (int r = 0; r < 4; ++r)
                    inter[(size_t)(x0 + w * 16 + lk * 4 + r) * NN + (k0 + nt * 16 + lrow)] = accI[nt][r];
        }
#pragma unroll
        for (int i = 0; i < 12; ++i) bc[i] = bn[i];
    }
    int xout = x0 + w * 16 + lk * 4;
#pragma unroll
    for (int ft = 0; ft < 5; ++ft)
#pragma unroll
        for (int r = 0; r < 4; ++r)
            atomicAdd(&afT[(size_t)(ft * 16 + lrow) * NN + xout + r], acc[ft][r]);
}

// ---------------- set2set pool (batch 1, h_d=160) ----------------

__global__ __launch_bounds__(64) void gates_pool_kernel(const float* __restrict__ Wih, const float* __restrict__ Whh,
                                                        const float* __restrict__ bih, const float* __restrict__ bhh,
                                                        const float* __restrict__ q, const float* __restrict__ h,
                                                        float* __restrict__ gts) {
    int j = blockIdx.x;
    int lane = threadIdx.x;
    const float* wi = Wih + j * 320;
    const float* wh = Whh + j * 160;
    float p = 0.f;
#pragma unroll
    for (int k4 = 0; k4 < 5; ++k4) { int k = lane + k4 * 64; p += wi[k] * q[k]; }
#pragma unroll
    for (int k4 = 0; k4 < 3; ++k4) { int k = lane + k4 * 64; if (k < 160) p += wh[k] * h[k]; }
    p = wsum(p);
    if (lane == 0) gts[j] = p + bih[j] + bhh[j];
}

__global__ __launch_bounds__(256) void pool_point_kernel(const float* __restrict__ gts, float* __restrict__ h,
                                                         float* __restrict__ c, float* __restrict__ q) {
    int tid = threadIdx.x;
    if (tid < 160) {
        float cn = sigm(gts[160 + tid]) * c[tid] + sigm(gts[tid]) * ftanh(gts[320 + tid]);
        c[tid] = cn;
        float hn = sigm(gts[480 + tid]) * ftanh(cn);
        h[tid] = hn;
        q[tid] = hn;   // q_star[0:160] = h
    }
}

__global__ __launch_bounds__(256) void pool_scores_kernel(const float* __restrict__ afT, const float* __restrict__ g,
                                                          const float* __restrict__ h, float* __restrict__ scores,
                                                          float* __restrict__ pmax) {
    int tid = threadIdx.x;
    int n = blockIdx.x * 256 + tid;
    float s = -3.4e38f;
    if (n < NN) {
        float acc = 0.f;
#pragma unroll 8
        for (int k = 0; k < 80; ++k) acc += afT[k * NN + n] * h[k];
        const float* gr = g + n * 80;
#pragma unroll 8
        for (int k = 0; k < 80; ++k) acc += gr[k] * h[80 + k];
        scores[n] = acc;
        s = acc;
    }
    __shared__ float red[4];
    float m = wmax(s);
    if ((tid & 63) == 0) red[tid >> 6] = m;
    __syncthreads();
    if (tid == 0) pmax[blockIdx.x] = fmaxf(fmaxf(red[0], red[1]), fmaxf(red[2], red[3]));
}

__global__ __launch_bounds__(256) void pool_softmax_kernel(float* __restrict__ scores, const float* __restrict__ pmax,
                                                           float* __restrict__ denom) {
    int tid = threadIdx.x;
    __shared__ float sm;
    __shared__ float red[4];
    float m = (tid < 32) ? pmax[tid] : -3.4e38f;
    m = wmax(m);
    if (tid == 0) sm = m;
    __syncthreads();
    float mm = sm;
    float lsum = 0.f;
    for (int n = tid; n < NN; n += 256) {
        float e = __expf(scores[n] - mm);
        scores[n] = e;
        lsum += e;
    }
    float w = wsum(lsum);
    if ((tid & 63) == 0) red[tid >> 6] = w;
    __syncthreads();
    if (tid == 0) denom[0] = red[0] + red[1] + red[2] + red[3];
}

__global__ __launch_bounds__(256) void pool_r_kernel(const float* __restrict__ afT, const float* __restrict__ g,
                                                     const float* __restrict__ scores, const float* __restrict__ denom,
                                                     float* __restrict__ q) {
    int f = blockIdx.x;   // 0..159
    int tid = threadIdx.x;
    float acc = 0.f;
    if (f < 80) {
        const float* x = afT + (size_t)f * NN;
        for (int n = tid; n < NN; n += 256) acc += scores[n] * x[n];
    } else {
        const float* x = g + (f - 80);
        for (int n = tid; n < NN; n += 256) acc += scores[n] * x[(size_t)n * 80];
    }
    float w = wsum(acc);
    __shared__ float red[4];
    if ((tid & 63) == 0) red[tid >> 6] = w;
    __syncthreads();
    if (tid == 0) q[160 + f] = (red[0] + red[1] + red[2] + red[3]) * rcp_fast(denom[0]);
}

// ---------------- final MLP (parallel per-row GEMVs) ----------------

__global__ __launch_bounds__(640) void concat_kernel(const float* __restrict__ cu, const float* __restrict__ cv,
                                                     float* __restrict__ x0) {
    int tid = threadIdx.x;
    x0[tid] = (tid < 320) ? cu[tid] : cv[tid - 320];
}

__global__ __launch_bounds__(64) void gemv_kernel(const float* __restrict__ W, const float* __restrict__ b,
                                                  const float* __restrict__ x, float* __restrict__ y,
                                                  int K, int relu) {
    int j = blockIdx.x;
    int lane = threadIdx.x;
    const float* w = W + (size_t)j * K;
    float p = 0.f;
    for (int k = lane; k < K; k += 64) p += w[k] * x[k];
    p = wsum(p);
    if (lane == 0) {
        p += b[j];
        y[j] = relu ? fmaxf(p, 0.f) : p;
    }
}

// ---------------- launch ----------------

extern "C" void kernel_launch(void* const* d_in, const int* in_sizes, int n_in,
                              void* d_out, int out_size, void* d_ws, size_t ws_size,
                              hipStream_t stream) {
    const float* nodes_u = (const float*)d_in[0];
    const int* ei_u = (const int*)d_in[1];
    const float* ef_u = (const float*)d_in[2];
    const float* nodes_v = (const float*)d_in[3];
    const int* ei_v = (const int*)d_in[4];
    const float* ef_v = (const float*)d_in[5];
    const float* Uw_u = (const float*)d_in[6];
    const float* Ub_u = (const float*)d_in[7];
    const float* Mw_u = (const float*)d_in[8];
    const float* Mb_u = (const float*)d_in[9];
    const float* Uw_v = (const float*)d_in[10];
    const float* Ub_v = (const float*)d_in[11];
    const float* Mw_v = (const float*)d_in[12];
    const float* Mb_v = (const float*)d_in[13];
    const float* lsWih = (const float*)d_in[14];
    const float* lsWhh = (const float*)d_in[15];
    const float* lsbih = (const float*)d_in[16];
    const float* lsbhh = (const float*)d_in[17];
    const float* lvWih = (const float*)d_in[18];
    const float* lvWhh = (const float*)d_in[19];
    const float* lvbih = (const float*)d_in[20];
    const float* lvbhh = (const float*)d_in[21];
    const float* gsWih = (const float*)d_in[22];
    const float* gsWhh = (const float*)d_in[23];
    const float* gsbih = (const float*)d_in[24];
    const float* gsbhh = (const float*)d_in[25];
    const float* gvWih = (const float*)d_in[26];
    const float* gvWhh = (const float*)d_in[27];
    const float* gvbih = (const float*)d_in[28];
    const float* gvbhh = (const float*)d_in[29];
    const float* w1 = (const float*)d_in[30];
    const float* b1 = (const float*)d_in[31];
    const float* w2 = (const float*)d_in[32];
    const float* b2 = (const float*)d_in[33];
    const float* w3 = (const float*)d_in[34];
    const float* b3 = (const float*)d_in[35];
    const float* w4 = (const float*)d_in[36];
    const float* b4 = (const float*)d_in[37];

    float* ws = (float*)d_ws;
    float* hA_u = ws + 0;
    float* hB_u = ws + 320000;
    float* hA_v = ws + 640000;
    float* hB_v = ws + 960000;
    float* msg  = ws + 1280000;
    float* Apro = ws + 1600000;
    float* Bpro = ws + 1920000;
    float* q_u  = ws + 2240000;   // gu [8000,80]
    float* q_v  = ws + 2880000;   // gv [8000,80]
    float* hh   = ws + 3520000;   // u-graph LSTM state
    float* cc   = ws + 3840000;
    float* gT   = ws + 4160000;   // gates transposed [160][8000] (s2s phase only)
    float* sef_u = ws + 4160000;  // [8000][10] — dead before s2s starts
    float* sef_v = ws + 4240000;  // [8000][10]
    float* uafT = ws + 5440000;   // [80][8000]
    float* vafT = ws + 6080000;   // [80][8000]
    float* scores = ws + 6720000;
    float* pmax = ws + 6728000;
    float* pden = ws + 6728032;
    float* pq_u = ws + 6728040;
    float* ph_u = ws + 6728360;
    float* pc_u = ws + 6728520;
    float* pq_v = ws + 6728680;
    float* ph_v = ws + 6729000;
    float* pc_v = ws + 6729160;
    float* pgts = ws + 6729320;   // 640
    float* mx0  = ws + 6729960;   // 640
    float* mx1  = ws + 6730600;   // 360
    float* mx2  = ws + 6730960;   // 200
    float* mx3  = ws + 6731160;   // 120
    int* ioff_u   = (int*)(ws + 6731280);   // 8001 (pad 8064)
    int* idlist_u = (int*)(ws + 6739344);   // 128000
    int* ioff_v   = (int*)(ws + 6867344);   // 8064
    int* idlist_v = (int*)(ws + 6875408);   // 128000
    int* iwoff    = (int*)(ws + 7003408);   // 8064
    int* ideg     = (int*)(ws + 7011472);   // 8064
    float* hh_v = ws + 7019536;   // v-graph LSTM state [320000]
    float* cc_v = ws + 7339536;   // [320000]

    // bf16 buffers reuse the (dead by then) message-passing region
    short* guT = (short*)(ws + 0);        // [80][8000]
    short* gvT = (short*)(ws + 320000);   // [80][8000]
    short* gub = (short*)(ws + 640000);   // [8000][96]
    short* gvb = (short*)(ws + 1024000);  // [8000][96]

    float* out = (float*)d_out;
    float* inter = out + 1;

    // ---- CSR + edge-feature sums: u ----
    hipMemsetAsync(ideg, 0, NN * sizeof(int), stream);
    hipMemsetAsync(sef_u, 0, NN * EDv * sizeof(float), stream);
    csr_deg_kernel<<<500, 256, 0, stream>>>(ei_u, ideg);
    csr_scan_kernel<<<1, 64, 0, stream>>>(ideg, ioff_u, iwoff);
    csr_fill_kernel<<<500, 256, 0, stream>>>(ei_u, iwoff, idlist_u);
    sef_kernel<<<5000, 256, 0, stream>>>(ei_u, ef_u, sef_u);
    // ---- CSR + edge-feature sums: v ----
    hipMemsetAsync(ideg, 0, NN * sizeof(int), stream);
    hipMemsetAsync(sef_v, 0, NN * EDv * sizeof(float), stream);
    csr_deg_kernel<<<500, 256, 0, stream>>>(ei_v, ideg);
    csr_scan_kernel<<<1, 64, 0, stream>>>(ideg, ioff_v, iwoff);
    csr_fill_kernel<<<500, 256, 0, stream>>>(ei_v, iwoff, idlist_v);
    sef_kernel<<<5000, 256, 0, stream>>>(ei_v, ef_v, sef_v);

    // ---- message passing: u ----
    {
        const float* cur = nodes_u;
        float* nxt[3] = {hA_u, hB_u, hA_u};
        for (int k = 0; k < 3; ++k) {
            node_proj_kernel<<<1250, 256, 0, stream>>>(cur, Uw_u + k * 3600, Apro, Bpro);
            msg_gather_kernel<<<1250, 256, 0, stream>>>(ioff_u, idlist_u, sef_u, Uw_u + k * 3600,
                                                        Ub_u + k * 40, Apro, Bpro, msg);
            node_update_kernel<<<1250, 256, 0, stream>>>(cur, msg, Mw_u + k * 3200, Mb_u + k * 40, nxt[k]);
            cur = nxt[k];
        }
    }
    // ---- message passing: v ----
    {
        const float* cur = nodes_v;
        float* nxt[3] = {hA_v, hB_v, hA_v};
        for (int k = 0; k < 3; ++k) {
            node_proj_kernel<<<1250, 256, 0, stream>>>(cur, Uw_v + k * 3600, Apro, Bpro);
            msg_gather_kernel<<<1250, 256, 0, stream>>>(ioff_v, idlist_v, sef_v, Uw_v + k * 3600,
                                                        Ub_v + k * 40, Apro, Bpro, msg);
            node_update_kernel<<<1250, 256, 0, stream>>>(cur, msg, Mw_v + k * 3200, Mb_v + k * 40, nxt[k]);
            cur = nxt[k];
        }
    }

    // ---- set2set pair (q_u,q_v,hh,cc contiguous -> one memset; v uses hh_v/cc_v) ----
    hipMemsetAsync(q_u, 0, 1920000 * sizeof(float), stream);     // q_u,q_v,hh,cc
    hipMemsetAsync(hh_v, 0, 640000 * sizeof(float), stream);     // hh_v,cc_v
    for (int stp = 0; stp < 2; ++stp) {
        s2s_gates_kernel<<<625, 256, 0, stream>>>(q_u, hh, lsWih, lsWhh, lsbih, lsbhh, gT);
        s2s_update_kernel<<<32, 256, 0, stream>>>(gT, nodes_u, hA_u, hh, cc, q_u);
    }
    for (int stp = 0; stp < 2; ++stp) {
        s2s_gates_kernel<<<625, 256, 0, stream>>>(q_v, hh_v, lvWih, lvWhh, lvbih, lvbhh, gT);
        s2s_update_kernel<<<32, 256, 0, stream>>>(gT, nodes_v, hA_v, hh_v, cc_v, q_v);
    }

    // ---- bf16 casts (u+v in one launch each) ----
    cast_t_kernel<<<dim3(2500, 2), 256, 0, stream>>>(q_u, q_v, guT, gvT);
    cast_pad_kernel<<<dim3(3000, 2), 256, 0, stream>>>(q_u, q_v, gub, gvb);

    // ---- fused interaction + after-features (both variants, one launch, SW-pipelined) ----
    hipMemsetAsync(uafT, 0, 1280000 * sizeof(float), stream);   // uafT + vafT contiguous
    fused_kernel<<<dim3(125, 8, 2), 256, 0, stream>>>(gub, gvb, guT, gvT, inter, uafT, vafT);

    // ---- pools ----
    hipMemsetAsync(pq_u, 0, 1280 * sizeof(float), stream);   // pq_u..pc_v contiguous
    for (int stp = 0; stp < 2; ++stp) {
        gates_pool_kernel<<<640, 64, 0, stream>>>(gsWih, gsWhh, gsbih, gsbhh, pq_u, ph_u, pgts);
        pool_point_kernel<<<1, 256, 0, stream>>>(pgts, ph_u, pc_u, pq_u);
        pool_scores_kernel<<<32, 256, 0, stream>>>(uafT, q_u, ph_u, scores, pmax);
        pool_softmax_kernel<<<1, 256, 0, stream>>>(scores, pmax, pden);
        pool_r_kernel<<<160, 256, 0, stream>>>(uafT, q_u, scores, pden, pq_u);
    }
    for (int stp = 0; stp < 2; ++stp) {
        gates_pool_kernel<<<640, 64, 0, stream>>>(gvWih, gvWhh, gvbih, gvbhh, pq_v, ph_v, pgts);
        pool_point_kernel<<<1, 256, 0, stream>>>(pgts, ph_v, pc_v, pq_v);
        pool_scores_kernel<<<32, 256, 0, stream>>>(vafT, q_v, ph_v, scores, pmax);
        pool_softmax_kernel<<<1, 256, 0, stream>>>(scores, pmax, pden);
        pool_r_kernel<<<160, 256, 0, stream>>>(vafT, q_v, scores, pden, pq_v);
    }

    // ---- final MLP ----
    concat_kernel<<<1, 640, 0, stream>>>(pq_u, pq_v, mx0);
    gemv_kernel<<<360, 64, 0, stream>>>(w1, b1, mx0, mx1, 640, 1);
    gemv_kernel<<<200, 64, 0, stream>>>(w2, b2, mx1, mx2, 360, 1);
    gemv_kernel<<<120, 64, 0, stream>>>(w3, b3, mx2, mx3, 200, 1);
    gemv_kernel<<<1, 64, 0, stream>>>(w4, b4, mx3, out, 120, 0);
}

// Round 11
// 800.826 us; speedup vs baseline: 1.5920x; 1.2217x over previous
//
#include <hip/hip_runtime.h>
#include <cstdint>
#include <cstddef>

#define NN 8000
#define NE 128000
#define NDv 40
#define EDv 10

typedef __attribute__((ext_vector_type(8))) short short8v;
typedef __attribute__((ext_vector_type(4))) float f32x4;

__device__ __forceinline__ float rcp_fast(float x) { return __builtin_amdgcn_rcpf(x); }
__device__ __forceinline__ float sigm(float x) { return rcp_fast(1.f + __expf(-x)); }
__device__ __forceinline__ float ftanh(float x) {
    float e = __expf(2.f * x);
    return 1.f - 2.f * rcp_fast(e + 1.f);
}
__device__ __forceinline__ short f2bf(float x) {   // RNE f32 -> bf16
    unsigned u = __builtin_bit_cast(unsigned, x);
    u += 0x7fffu + ((u >> 16) & 1u);
    return (short)(u >> 16);
}
__device__ __forceinline__ float wsum(float v) {
    for (int o = 32; o; o >>= 1) v += __shfl_down(v, o);
    return v;
}
__device__ __forceinline__ float wmax(float v) {
    for (int o = 32; o; o >>= 1) v = fmaxf(v, __shfl_down(v, o));
    return v;
}

// ---------------- CSR build (paired u/v via blockIdx.y) ----------------

__global__ __launch_bounds__(256) void csr_deg2_kernel(const int* __restrict__ ei_u, const int* __restrict__ ei_v,
                                                       int* __restrict__ deg_u, int* __restrict__ deg_v) {
    const int* ei = blockIdx.y ? ei_v : ei_u;
    int* deg = blockIdx.y ? deg_v : deg_u;
    int e = blockIdx.x * 256 + threadIdx.x;
    if (e < NE) atomicAdd(&deg[ei[e]], 1);
}

__global__ __launch_bounds__(64) void csr_scan2_kernel(const int* __restrict__ deg_u, const int* __restrict__ deg_v,
                                                       int* __restrict__ off_u, int* __restrict__ off_v,
                                                       int* __restrict__ woff_u, int* __restrict__ woff_v) {
    const int* deg = blockIdx.x ? deg_v : deg_u;
    int* off = blockIdx.x ? off_v : off_u;
    int* woff = blockIdx.x ? woff_v : woff_u;
    int l = threadIdx.x;
    int base = l * 125;
    int s = 0;
    for (int i = 0; i < 125; ++i) s += deg[base + i];
    int pre = s;
    for (int o = 1; o < 64; o <<= 1) { int t = __shfl_up(pre, o); if (l >= o) pre += t; }
    pre -= s;   // exclusive prefix
    int run = pre;
    for (int i = 0; i < 125; ++i) {
        off[base + i] = run; woff[base + i] = run;
        run += deg[base + i];
    }
    if (l == 63) off[NN] = run;
}

__global__ __launch_bounds__(256) void csr_fill2_kernel(const int* __restrict__ ei_u, const int* __restrict__ ei_v,
                                                        int* __restrict__ woff_u, int* __restrict__ woff_v,
                                                        int* __restrict__ dl_u, int* __restrict__ dl_v) {
    const int* ei = blockIdx.y ? ei_v : ei_u;
    int* woff = blockIdx.y ? woff_v : woff_u;
    int* dlist = blockIdx.y ? dl_v : dl_u;
    int e = blockIdx.x * 256 + threadIdx.x;
    if (e < NE) { int p = atomicAdd(&woff[ei[e]], 1); dlist[p] = ei[NE + e]; }
}

__global__ __launch_bounds__(256) void sef2_kernel(const int* __restrict__ ei_u, const int* __restrict__ ei_v,
                                                   const float* __restrict__ ef_u, const float* __restrict__ ef_v,
                                                   float* __restrict__ sef_u, float* __restrict__ sef_v) {
    const int* ei = blockIdx.y ? ei_v : ei_u;
    const float* ef = blockIdx.y ? ef_v : ef_u;
    float* sef = blockIdx.y ? sef_v : sef_u;
    int t = blockIdx.x * 256 + threadIdx.x;   // exactly NE*EDv
    int e = t / EDv, k = t % EDv;
    atomicAdd(&sef[ei[e] * EDv + k], ef[t]);
}

// ---------------- message passing (paired) ----------------

__global__ __launch_bounds__(256) void node_proj2_kernel(const float* __restrict__ h_u, const float* __restrict__ h_v,
                                                         const float* __restrict__ Uw_u, const float* __restrict__ Uw_v,
                                                         float* __restrict__ A_u, float* __restrict__ B_u,
                                                         float* __restrict__ A_v, float* __restrict__ B_v) {
    const float* h = blockIdx.y ? h_v : h_u;
    const float* Uw = blockIdx.y ? Uw_v : Uw_u;
    float* A = blockIdx.y ? A_v : A_u;
    float* B = blockIdx.y ? B_v : B_u;
    __shared__ float W[40][81];   // 81-pad -> conflict-free strided reads
    int tid = threadIdx.x;
    for (int s = tid; s < 3200; s += 256) W[s / 80][s % 80] = Uw[(s / 80) * 90 + (s % 80)];
    __syncthreads();
    int t = blockIdx.x * 256 + tid;   // exactly 8000*40
    int n = t / NDv, i = t % NDv;
    float hreg[40];
    const float* hr = h + n * NDv;
#pragma unroll
    for (int k4 = 0; k4 < 10; ++k4) {
        float4 v = *reinterpret_cast<const float4*>(hr + k4 * 4);
        hreg[k4 * 4 + 0] = v.x; hreg[k4 * 4 + 1] = v.y; hreg[k4 * 4 + 2] = v.z; hreg[k4 * 4 + 3] = v.w;
    }
    float a = 0.f, b = 0.f;
#pragma unroll
    for (int k = 0; k < NDv; ++k) { a += W[i][k] * hreg[k]; b += W[i][40 + k] * hreg[k]; }
    A[t] = a; B[t] = b;
}

__global__ __launch_bounds__(256) void msg_gather2_kernel(const int* __restrict__ off_u, const int* __restrict__ dl_u,
                                                          const float* __restrict__ sef_u,
                                                          const float* __restrict__ Uw_u, const float* __restrict__ Ub_u,
                                                          const float* __restrict__ A_u, const float* __restrict__ B_u,
                                                          float* __restrict__ msg_u,
                                                          const int* __restrict__ off_v, const int* __restrict__ dl_v,
                                                          const float* __restrict__ sef_v,
                                                          const float* __restrict__ Uw_v, const float* __restrict__ Ub_v,
                                                          const float* __restrict__ A_v, const float* __restrict__ B_v,
                                                          float* __restrict__ msg_v) {
    const int* off = blockIdx.y ? off_v : off_u;
    const int* dlist = blockIdx.y ? dl_v : dl_u;
    const float* sef = blockIdx.y ? sef_v : sef_u;
    const float* Uw = blockIdx.y ? Uw_v : Uw_u;
    const float* Ub = blockIdx.y ? Ub_v : Ub_u;
    const float* A = blockIdx.y ? A_v : A_u;
    const float* B = blockIdx.y ? B_v : B_u;
    float* msg = blockIdx.y ? msg_v : msg_u;
    int t = blockIdx.x * 256 + threadIdx.x;   // exactly 8000*40
    int n = t / NDv, i = t % NDv;
    const float* we = Uw + i * 90 + 80;
    const float* se = sef + n * EDv;
    int p0 = off[n], p1 = off[n + 1];
    float acc = (float)(p1 - p0) * (A[t] + Ub[i]);
#pragma unroll
    for (int k = 0; k < EDv; ++k) acc += we[k] * se[k];
    for (int p = p0; p < p1; ++p) acc += B[dlist[p] * NDv + i];
    msg[t] = acc;
}

__global__ __launch_bounds__(256) void node_update2_kernel(const float* __restrict__ h_u, const float* __restrict__ msg_u,
                                                           const float* __restrict__ Mw_u, const float* __restrict__ Mb_u,
                                                           float* __restrict__ hout_u,
                                                           const float* __restrict__ h_v, const float* __restrict__ msg_v,
                                                           const float* __restrict__ Mw_v, const float* __restrict__ Mb_v,
                                                           float* __restrict__ hout_v) {
    const float* h = blockIdx.y ? h_v : h_u;
    const float* msg = blockIdx.y ? msg_v : msg_u;
    const float* Mw = blockIdx.y ? Mw_v : Mw_u;
    const float* Mb = blockIdx.y ? Mb_v : Mb_u;
    float* hout = blockIdx.y ? hout_v : hout_u;
    __shared__ float W[40][81];
    int tid = threadIdx.x;
    for (int s = tid; s < 3200; s += 256) W[s / 80][s % 80] = Mw[s];
    __syncthreads();
    int t = blockIdx.x * 256 + tid;   // exactly 8000*40
    int n = t / NDv, i = t % NDv;
    const float* hr = h + n * NDv;
    const float* mr = msg + n * NDv;
    float acc = Mb[i];
#pragma unroll
    for (int k = 0; k < NDv; ++k) acc += W[i][k] * hr[k];
#pragma unroll
    for (int k = 0; k < NDv; ++k) acc += W[i][40 + k] * mr[k];
    hout[t] = fmaxf(acc, 0.f);
}

// ---------------- set2set (pair, per-node LSTM h_d=40; paired u/v) ----------------

__global__ __launch_bounds__(256) void s2s_gates2_kernel(const float* __restrict__ q_u, const float* __restrict__ hh_u,
                                                         const float* __restrict__ Wih_u, const float* __restrict__ Whh_u,
                                                         const float* __restrict__ bih_u, const float* __restrict__ bhh_u,
                                                         float* __restrict__ gT_u,
                                                         const float* __restrict__ q_v, const float* __restrict__ hh_v,
                                                         const float* __restrict__ Wih_v, const float* __restrict__ Whh_v,
                                                         const float* __restrict__ bih_v, const float* __restrict__ bhh_v,
                                                         float* __restrict__ gT_v) {
    const float* q = blockIdx.y ? q_v : q_u;
    const float* hh = blockIdx.y ? hh_v : hh_u;
    const float* Wih = blockIdx.y ? Wih_v : Wih_u;
    const float* Whh = blockIdx.y ? Whh_v : Whh_u;
    const float* bih = blockIdx.y ? bih_v : bih_u;
    const float* bhh = blockIdx.y ? bhh_v : bhh_u;
    float* gatesT = blockIdx.y ? gT_v : gT_u;
    int t = blockIdx.x * 256 + threadIdx.x;   // exactly 8000*20
    int n = t % NN;
    int jg = t / NN;
    float qr[80];
#pragma unroll
    for (int k4 = 0; k4 < 20; ++k4) {
        float4 v = *reinterpret_cast<const float4*>(q + n * 80 + k4 * 4);
        qr[k4 * 4 + 0] = v.x; qr[k4 * 4 + 1] = v.y; qr[k4 * 4 + 2] = v.z; qr[k4 * 4 + 3] = v.w;
    }
    float hr[40];
#pragma unroll
    for (int k4 = 0; k4 < 10; ++k4) {
        float4 v = *reinterpret_cast<const float4*>(hh + n * 40 + k4 * 4);
        hr[k4 * 4 + 0] = v.x; hr[k4 * 4 + 1] = v.y; hr[k4 * 4 + 2] = v.z; hr[k4 * 4 + 3] = v.w;
    }
#pragma unroll
    for (int jj = 0; jj < 8; ++jj) {
        int j = jg * 8 + jj;
        const float* wi = Wih + j * 80;
        const float* wh = Whh + j * 40;
        float acc = bih[j] + bhh[j];
#pragma unroll
        for (int k = 0; k < 80; ++k) acc += wi[k] * qr[k];
#pragma unroll
        for (int k = 0; k < 40; ++k) acc += wh[k] * hr[k];
        gatesT[j * NN + n] = acc;
    }
}

__global__ __launch_bounds__(256) void s2s_update2_kernel(const float* __restrict__ gT_u, const float* __restrict__ h0_u,
                                                          const float* __restrict__ ht_u, float* __restrict__ hh_u,
                                                          float* __restrict__ cc_u, float* __restrict__ q_u,
                                                          const float* __restrict__ gT_v, const float* __restrict__ h0_v,
                                                          const float* __restrict__ ht_v, float* __restrict__ hh_v,
                                                          float* __restrict__ cc_v, float* __restrict__ q_v) {
    const float* gatesT = blockIdx.y ? gT_v : gT_u;
    const float* h0 = blockIdx.y ? h0_v : h0_u;
    const float* ht = blockIdx.y ? ht_v : ht_u;
    float* hh = blockIdx.y ? hh_v : hh_u;
    float* cc = blockIdx.y ? cc_v : cc_u;
    float* q = blockIdx.y ? q_v : q_u;
    int n = blockIdx.x * 256 + threadIdx.x;
    if (n >= NN) return;
    float hreg[40];
    float e0 = 0.f, e1 = 0.f;
#pragma unroll
    for (int i = 0; i < 40; ++i) {
        float gi = gatesT[i * NN + n];
        float gf = gatesT[(40 + i) * NN + n];
        float gg = gatesT[(80 + i) * NN + n];
        float go = gatesT[(120 + i) * NN + n];
        float cn = sigm(gf) * cc[n * 40 + i] + sigm(gi) * ftanh(gg);
        cc[n * 40 + i] = cn;
        float hn = sigm(go) * ftanh(cn);
        hreg[i] = hn;
        e0 += h0[n * 40 + i] * hn;
        e1 += ht[n * 40 + i] * hn;
    }
    float m = fmaxf(e0, e1);
    float p0 = __expf(e0 - m), p1 = __expf(e1 - m);
    float inv = rcp_fast(p0 + p1);
    float a0 = p0 * inv, a1 = p1 * inv;
#pragma unroll
    for (int i = 0; i < 40; ++i) {
        hh[n * 40 + i] = hreg[i];
        q[n * 80 + i] = hreg[i];
        q[n * 80 + 40 + i] = a0 * h0[n * 40 + i] + a1 * ht[n * 40 + i];
    }
}

// ---------------- bf16 casts (u and v via blockIdx.y) ----------------

__global__ __launch_bounds__(256) void cast_pad_kernel(const float* __restrict__ gu, const float* __restrict__ gv,
                                                       short* __restrict__ ou, short* __restrict__ ov) {
    int t = blockIdx.x * 256 + threadIdx.x;   // exactly 8000*96
    const float* g = blockIdx.y ? gv : gu;
    short* o = blockIdx.y ? ov : ou;
    int m = t / 96, k = t % 96;
    o[t] = (k < 80) ? f2bf(g[m * 80 + k]) : (short)0;
}

__global__ __launch_bounds__(256) void cast_t_kernel(const float* __restrict__ gu, const float* __restrict__ gv,
                                                     short* __restrict__ ou, short* __restrict__ ov) {
    int t = blockIdx.x * 256 + threadIdx.x;   // exactly 80*8000
    const float* g = blockIdx.y ? gv : gu;
    short* o = blockIdx.y ? ov : ou;
    int m = t % NN, f = t / NN;
    o[t] = f2bf(g[m * 80 + f]);
}

// ---------------- fused interaction + after-feature (barrier-free, SW-pipelined) ----------------
// blockIdx.z = 0: I = gu@gv^T (stored) + u_afterT;  z = 1: I^T recomputed + v_afterT.
// Issue order loads-first / stores-last; wave-private P (no __syncthreads).

__global__ __launch_bounds__(256, 2) void fused_kernel(const short* __restrict__ gub, const short* __restrict__ gvb,
                                                       const short* __restrict__ guT, const short* __restrict__ gvT,
                                                       float* __restrict__ inter,
                                                       float* __restrict__ uafT, float* __restrict__ vafT) {
    __shared__ short P[4][16][72];   // per-wave [row][col], 144B row stride
    const short* Xb; const short* Yb; const short* YT; float* afT;
    bool storeI = (blockIdx.z == 0);
    if (storeI) { Xb = gub; Yb = gvb; YT = gvT; afT = uafT; }
    else        { Xb = gvb; Yb = gub; YT = guT; afT = vafT; }
    int tid = threadIdx.x;
    int w = tid >> 6, l = tid & 63;
    int lrow = l & 15, lk = l >> 4;
    int x0 = blockIdx.x * 64;
    int it0 = (125 * blockIdx.y) >> 3;
    int it1 = (125 * (blockIdx.y + 1)) >> 3;
    short8v a_x[3];
    const short* arow = Xb + (size_t)(x0 + w * 16 + lrow) * 96 + lk * 8;
#pragma unroll
    for (int ks = 0; ks < 3; ++ks) a_x[ks] = *reinterpret_cast<const short8v*>(arow + ks * 32);
    const short* ybase = Yb + (size_t)lrow * 96 + lk * 8;

    f32x4 acc[5] = {};
    short8v bc[12], bn[12];
#pragma unroll
    for (int i = 0; i < 12; ++i) {
        int ks = i >> 2, nt = i & 3;
        bc[i] = *reinterpret_cast<const short8v*>(ybase + (size_t)(it0 * 64 + nt * 16) * 96 + ks * 32);
    }
    for (int it = it0; it < it1; ++it) {
        int k0 = it * 64;
        if (it + 1 < it1) {
#pragma unroll
            for (int i = 0; i < 12; ++i) {
                int ks = i >> 2, nt = i & 3;
                bn[i] = *reinterpret_cast<const short8v*>(ybase + (size_t)(k0 + 64 + nt * 16) * 96 + ks * 32);
            }
        }
        short8v byt[10];
#pragma unroll
        for (int ks2 = 0; ks2 < 2; ++ks2)
#pragma unroll
            for (int ft = 0; ft < 5; ++ft)
                byt[ks2 * 5 + ft] = *reinterpret_cast<const short8v*>(YT + (size_t)(ft * 16 + lrow) * NN + k0 + ks2 * 32 + lk * 8);
        f32x4 accI[4] = {};
#pragma unroll
        for (int ks = 0; ks < 3; ++ks)
#pragma unroll
            for (int nt = 0; nt < 4; ++nt)
                accI[nt] = __builtin_amdgcn_mfma_f32_16x16x32_bf16(a_x[ks], bc[ks * 4 + nt], accI[nt], 0, 0, 0);
#pragma unroll
        for (int nt = 0; nt < 4; ++nt)
#pragma unroll
            for (int r = 0; r < 4; ++r)
                P[w][lk * 4 + r][nt * 16 + lrow] = f2bf(ftanh(accI[nt][r]));
        // wave-private LDS: same-wave write->read is in-order, no barrier needed
#pragma unroll
        for (int ks2 = 0; ks2 < 2; ++ks2) {
            short8v ap = *reinterpret_cast<const short8v*>(&P[w][lrow][ks2 * 32 + lk * 8]);
#pragma unroll
            for (int ft = 0; ft < 5; ++ft)
                acc[ft] = __builtin_amdgcn_mfma_f32_16x16x32_bf16(ap, byt[ks2 * 5 + ft], acc[ft], 0, 0, 0);
        }
        if (storeI) {
#pragma unroll
            for (int nt = 0; nt < 4; ++nt)
#pragma unroll
                for (int r = 0; r < 4; ++r)
                    inter[(size_t)(x0 + w * 16 + lk * 4 + r) * NN + (k0 + nt * 16 + lrow)] = accI[nt][r];
        }
#pragma unroll
        for (int i = 0; i < 12; ++i) bc[i] = bn[i];
    }
    int xout = x0 + w * 16 + lk * 4;
#pragma unroll
    for (int ft = 0; ft < 5; ++ft)
#pragma unroll
        for (int r = 0; r < 4; ++r)
            atomicAdd(&afT[(size_t)(ft * 16 + lrow) * NN + xout + r], acc[ft][r]);
}

// ---------------- set2set pool (batch 1, h_d=160; paired u/v) ----------------

__global__ __launch_bounds__(64) void gates_pool2_kernel(const float* __restrict__ Wih_u, const float* __restrict__ Whh_u,
                                                         const float* __restrict__ bih_u, const float* __restrict__ bhh_u,
                                                         const float* __restrict__ q_u, const float* __restrict__ h_u,
                                                         const float* __restrict__ Wih_v, const float* __restrict__ Whh_v,
                                                         const float* __restrict__ bih_v, const float* __restrict__ bhh_v,
                                                         const float* __restrict__ q_v, const float* __restrict__ h_v,
                                                         float* __restrict__ gts2) {
    const float* Wih = blockIdx.y ? Wih_v : Wih_u;
    const float* Whh = blockIdx.y ? Whh_v : Whh_u;
    const float* bih = blockIdx.y ? bih_v : bih_u;
    const float* bhh = blockIdx.y ? bhh_v : bhh_u;
    const float* q = blockIdx.y ? q_v : q_u;
    const float* h = blockIdx.y ? h_v : h_u;
    float* gts = gts2 + blockIdx.y * 640;
    int j = blockIdx.x;
    int lane = threadIdx.x;
    const float* wi = Wih + j * 320;
    const float* wh = Whh + j * 160;
    float p = 0.f;
#pragma unroll
    for (int k4 = 0; k4 < 5; ++k4) { int k = lane + k4 * 64; p += wi[k] * q[k]; }
#pragma unroll
    for (int k4 = 0; k4 < 3; ++k4) { int k = lane + k4 * 64; if (k < 160) p += wh[k] * h[k]; }
    p = wsum(p);
    if (lane == 0) gts[j] = p + bih[j] + bhh[j];
}

__global__ __launch_bounds__(256) void pool_point2_kernel(const float* __restrict__ gts2,
                                                          float* __restrict__ h_u, float* __restrict__ c_u,
                                                          float* __restrict__ q_u,
                                                          float* __restrict__ h_v, float* __restrict__ c_v,
                                                          float* __restrict__ q_v) {
    const float* gts = gts2 + blockIdx.y * 640;
    float* h = blockIdx.y ? h_v : h_u;
    float* c = blockIdx.y ? c_v : c_u;
    float* q = blockIdx.y ? q_v : q_u;
    int tid = threadIdx.x;
    if (tid < 160) {
        float cn = sigm(gts[160 + tid]) * c[tid] + sigm(gts[tid]) * ftanh(gts[320 + tid]);
        c[tid] = cn;
        float hn = sigm(gts[480 + tid]) * ftanh(cn);
        h[tid] = hn;
        q[tid] = hn;   // q_star[0:160] = h
    }
}

__global__ __launch_bounds__(256) void pool_scores2_kernel(const float* __restrict__ uafT, const float* __restrict__ g_u,
                                                           const float* __restrict__ h_u, float* __restrict__ sc_u,
                                                           const float* __restrict__ vafT, const float* __restrict__ g_v,
                                                           const float* __restrict__ h_v, float* __restrict__ sc_v,
                                                           float* __restrict__ pmax2) {
    const float* afT = blockIdx.y ? vafT : uafT;
    const float* g = blockIdx.y ? g_v : g_u;
    const float* h = blockIdx.y ? h_v : h_u;
    float* scores = blockIdx.y ? sc_v : sc_u;
    float* pmax = pmax2 + blockIdx.y * 32;
    int tid = threadIdx.x;
    int n = blockIdx.x * 256 + tid;
    float s = -3.4e38f;
    if (n < NN) {
        float acc = 0.f;
#pragma unroll 8
        for (int k = 0; k < 80; ++k) acc += afT[k * NN + n] * h[k];
        const float* gr = g + n * 80;
#pragma unroll 8
        for (int k = 0; k < 80; ++k) acc += gr[k] * h[80 + k];
        scores[n] = acc;
        s = acc;
    }
    __shared__ float red[4];
    float m = wmax(s);
    if ((tid & 63) == 0) red[tid >> 6] = m;
    __syncthreads();
    if (tid == 0) pmax[blockIdx.x] = fmaxf(fmaxf(red[0], red[1]), fmaxf(red[2], red[3]));
}

__global__ __launch_bounds__(256) void pool_softmax2_kernel(float* __restrict__ sc_u, float* __restrict__ sc_v,
                                                            const float* __restrict__ pmax2, float* __restrict__ pden2) {
    float* scores = blockIdx.y ? sc_v : sc_u;
    const float* pmax = pmax2 + blockIdx.y * 32;
    float* denom = pden2 + blockIdx.y;
    int tid = threadIdx.x;
    __shared__ float sm;
    __shared__ float red[4];
    float m = (tid < 32) ? pmax[tid] : -3.4e38f;
    m = wmax(m);
    if (tid == 0) sm = m;
    __syncthreads();
    float mm = sm;
    float lsum = 0.f;
    for (int n = tid; n < NN; n += 256) {
        float e = __expf(scores[n] - mm);
        scores[n] = e;
        lsum += e;
    }
    float w = wsum(lsum);
    if ((tid & 63) == 0) red[tid >> 6] = w;
    __syncthreads();
    if (tid == 0) denom[0] = red[0] + red[1] + red[2] + red[3];
}

__global__ __launch_bounds__(256) void pool_r2_kernel(const float* __restrict__ uafT, const float* __restrict__ g_u,
                                                      const float* __restrict__ sc_u,
                                                      const float* __restrict__ vafT, const float* __restrict__ g_v,
                                                      const float* __restrict__ sc_v,
                                                      const float* __restrict__ pden2,
                                                      float* __restrict__ pq_u, float* __restrict__ pq_v) {
    const float* afT = blockIdx.y ? vafT : uafT;
    const float* g = blockIdx.y ? g_v : g_u;
    const float* scores = blockIdx.y ? sc_v : sc_u;
    float* q = blockIdx.y ? pq_v : pq_u;
    float den = pden2[blockIdx.y];
    int f = blockIdx.x;   // 0..159
    int tid = threadIdx.x;
    float acc = 0.f;
    if (f < 80) {
        const float* x = afT + (size_t)f * NN;
        for (int n = tid; n < NN; n += 256) acc += scores[n] * x[n];
    } else {
        const float* x = g + (f - 80);
        for (int n = tid; n < NN; n += 256) acc += scores[n] * x[(size_t)n * 80];
    }
    float w = wsum(acc);
    __shared__ float red[4];
    if ((tid & 63) == 0) red[tid >> 6] = w;
    __syncthreads();
    if (tid == 0) q[160 + f] = (red[0] + red[1] + red[2] + red[3]) * rcp_fast(den);
}

// ---------------- final MLP (parallel per-row GEMVs) ----------------

__global__ __launch_bounds__(640) void concat_kernel(const float* __restrict__ cu, const float* __restrict__ cv,
                                                     float* __restrict__ x0) {
    int tid = threadIdx.x;
    x0[tid] = (tid < 320) ? cu[tid] : cv[tid - 320];
}

__global__ __launch_bounds__(64) void gemv_kernel(const float* __restrict__ W, const float* __restrict__ b,
                                                  const float* __restrict__ x, float* __restrict__ y,
                                                  int K, int relu) {
    int j = blockIdx.x;
    int lane = threadIdx.x;
    const float* w = W + (size_t)j * K;
    float p = 0.f;
    for (int k = lane; k < K; k += 64) p += w[k] * x[k];
    p = wsum(p);
    if (lane == 0) {
        p += b[j];
        y[j] = relu ? fmaxf(p, 0.f) : p;
    }
}

// ---------------- launch ----------------

extern "C" void kernel_launch(void* const* d_in, const int* in_sizes, int n_in,
                              void* d_out, int out_size, void* d_ws, size_t ws_size,
                              hipStream_t stream) {
    const float* nodes_u = (const float*)d_in[0];
    const int* ei_u = (const int*)d_in[1];
    const float* ef_u = (const float*)d_in[2];
    const float* nodes_v = (const float*)d_in[3];
    const int* ei_v = (const int*)d_in[4];
    const float* ef_v = (const float*)d_in[5];
    const float* Uw_u = (const float*)d_in[6];
    const float* Ub_u = (const float*)d_in[7];
    const float* Mw_u = (const float*)d_in[8];
    const float* Mb_u = (const float*)d_in[9];
    const float* Uw_v = (const float*)d_in[10];
    const float* Ub_v = (const float*)d_in[11];
    const float* Mw_v = (const float*)d_in[12];
    const float* Mb_v = (const float*)d_in[13];
    const float* lsWih = (const float*)d_in[14];
    const float* lsWhh = (const float*)d_in[15];
    const float* lsbih = (const float*)d_in[16];
    const float* lsbhh = (const float*)d_in[17];
    const float* lvWih = (const float*)d_in[18];
    const float* lvWhh = (const float*)d_in[19];
    const float* lvbih = (const float*)d_in[20];
    const float* lvbhh = (const float*)d_in[21];
    const float* gsWih = (const float*)d_in[22];
    const float* gsWhh = (const float*)d_in[23];
    const float* gsbih = (const float*)d_in[24];
    const float* gsbhh = (const float*)d_in[25];
    const float* gvWih = (const float*)d_in[26];
    const float* gvWhh = (const float*)d_in[27];
    const float* gvbih = (const float*)d_in[28];
    const float* gvbhh = (const float*)d_in[29];
    const float* w1 = (const float*)d_in[30];
    const float* b1 = (const float*)d_in[31];
    const float* w2 = (const float*)d_in[32];
    const float* b2 = (const float*)d_in[33];
    const float* w3 = (const float*)d_in[34];
    const float* b3 = (const float*)d_in[35];
    const float* w4 = (const float*)d_in[36];
    const float* b4 = (const float*)d_in[37];

    float* ws = (float*)d_ws;
    float* hA_u = ws + 0;
    float* hB_u = ws + 320000;
    float* hA_v = ws + 640000;
    float* hB_v = ws + 960000;
    float* msg_u  = ws + 1280000;
    float* Apro_u = ws + 1600000;
    float* Bpro_u = ws + 1920000;
    float* q_u  = ws + 2240000;   // gu [8000,80]
    float* q_v  = ws + 2880000;   // gv [8000,80]
    float* hh_u = ws + 3520000;
    float* cc_u = ws + 3840000;
    float* sef_u = ws + 4160000;  // [8000][10] — MP phase
    float* sef_v = ws + 4240000;  // [8000][10]
    float* gT_u = ws + 4160000;   // [160][8000] — s2s phase (sef dead)
    float* gT_v = ws + 5440000;   // [160][8000] — overlaps uafT/vafT (memset later)
    float* uafT = ws + 5440000;   // [80][8000] — fused phase (gT_v dead)
    float* vafT = ws + 6080000;   // [80][8000]
    float* sc_u = ws + 6720000;   // [8000]
    float* sc_v = ws + 6728000;   // [8000]
    float* pmax2 = ws + 6736000;  // [2][32]
    float* pden2 = ws + 6736064;  // [2]
    float* pq_u = ws + 6736080;   // [320]
    float* ph_u = ws + 6736400;   // [160]
    float* pc_u = ws + 6736560;   // [160]
    float* pq_v = ws + 6736720;   // [320]
    float* ph_v = ws + 6737040;   // [160]
    float* pc_v = ws + 6737200;   // [160]
    float* pgts2 = ws + 6737360;  // [2][640]
    float* mx0  = ws + 6738640;   // 640
    float* mx1  = ws + 6739280;   // 360
    float* mx2  = ws + 6739640;   // 200
    float* mx3  = ws + 6739840;   // 120
    int* ioff_u   = (int*)(ws + 6740000);   // 8064
    int* idlist_u = (int*)(ws + 6748064);   // 128000
    int* ioff_v   = (int*)(ws + 6876064);   // 8064
    int* idlist_v = (int*)(ws + 6884128);   // 128000
    int* iwoff_u  = (int*)(ws + 7012128);   // 8064 (CSR phase only)
    int* ideg_u   = (int*)(ws + 7020192);   // 8064
    int* iwoff_v  = (int*)(ws + 7028256);   // 8064
    int* ideg_v   = (int*)(ws + 7036320);   // 8064 -> ends 7044384
    // MP phase (CSR ints above partly dead by then):
    float* msg_v  = ws + 7019536;   // [320000] (overlaps ideg_u..ideg_v, dead after CSR)
    float* Apro_v = ws + 7339536;   // [320000]
    float* Bpro_v = ws + 7659536;   // [320000] -> ends 7979536
    // s2s phase (MP v-buffers dead):
    float* hh_v = ws + 7019536;     // [320000]
    float* cc_v = ws + 7339536;     // [320000]

    // bf16 buffers reuse the (dead by then) message-passing region
    short* guT = (short*)(ws + 0);        // [80][8000]
    short* gvT = (short*)(ws + 320000);   // [80][8000]
    short* gub = (short*)(ws + 640000);   // [8000][96]
    short* gvb = (short*)(ws + 1024000);  // [8000][96]

    float* out = (float*)d_out;
    float* inter = out + 1;

    // ---- CSR + edge-feature sums (paired) ----
    hipMemsetAsync(ideg_u, 0, (7044384 - 7020192) * sizeof(int), stream);  // ideg_u, iwoff_v, ideg_v
    hipMemsetAsync(sef_u, 0, 2 * NN * EDv * sizeof(float), stream);        // sef_u + sef_v
    csr_deg2_kernel<<<dim3(500, 2), 256, 0, stream>>>(ei_u, ei_v, ideg_u, ideg_v);
    csr_scan2_kernel<<<2, 64, 0, stream>>>(ideg_u, ideg_v, ioff_u, ioff_v, iwoff_u, iwoff_v);
    csr_fill2_kernel<<<dim3(500, 2), 256, 0, stream>>>(ei_u, ei_v, iwoff_u, iwoff_v, idlist_u, idlist_v);
    sef2_kernel<<<dim3(5000, 2), 256, 0, stream>>>(ei_u, ei_v, ef_u, ef_v, sef_u, sef_v);

    // ---- message passing (paired u/v per round) ----
    {
        const float* cur_u = nodes_u;
        const float* cur_v = nodes_v;
        float* nxt_u[3] = {hA_u, hB_u, hA_u};
        float* nxt_v[3] = {hA_v, hB_v, hA_v};
        for (int k = 0; k < 3; ++k) {
            node_proj2_kernel<<<dim3(1250, 2), 256, 0, stream>>>(cur_u, cur_v, Uw_u + k * 3600, Uw_v + k * 3600,
                                                                 Apro_u, Bpro_u, Apro_v, Bpro_v);
            msg_gather2_kernel<<<dim3(1250, 2), 256, 0, stream>>>(ioff_u, idlist_u, sef_u, Uw_u + k * 3600,
                                                                  Ub_u + k * 40, Apro_u, Bpro_u, msg_u,
                                                                  ioff_v, idlist_v, sef_v, Uw_v + k * 3600,
                                                                  Ub_v + k * 40, Apro_v, Bpro_v, msg_v);
            node_update2_kernel<<<dim3(1250, 2), 256, 0, stream>>>(cur_u, msg_u, Mw_u + k * 3200, Mb_u + k * 40, nxt_u[k],
                                                                   cur_v, msg_v, Mw_v + k * 3200, Mb_v + k * 40, nxt_v[k]);
            cur_u = nxt_u[k];
            cur_v = nxt_v[k];
        }
    }

    // ---- set2set pair (paired u/v) ----
    hipMemsetAsync(q_u, 0, 1920000 * sizeof(float), stream);     // q_u,q_v,hh_u,cc_u
    hipMemsetAsync(hh_v, 0, 640000 * sizeof(float), stream);     // hh_v,cc_v
    for (int stp = 0; stp < 2; ++stp) {
        s2s_gates2_kernel<<<dim3(625, 2), 256, 0, stream>>>(q_u, hh_u, lsWih, lsWhh, lsbih, lsbhh, gT_u,
                                                            q_v, hh_v, lvWih, lvWhh, lvbih, lvbhh, gT_v);
        s2s_update2_kernel<<<dim3(32, 2), 256, 0, stream>>>(gT_u, nodes_u, hA_u, hh_u, cc_u, q_u,
                                                            gT_v, nodes_v, hA_v, hh_v, cc_v, q_v);
    }

    // ---- bf16 casts (u+v in one launch each) ----
    cast_t_kernel<<<dim3(2500, 2), 256, 0, stream>>>(q_u, q_v, guT, gvT);
    cast_pad_kernel<<<dim3(3000, 2), 256, 0, stream>>>(q_u, q_v, gub, gvb);

    // ---- fused interaction + after-features (both variants, one launch, SW-pipelined) ----
    hipMemsetAsync(uafT, 0, 1280000 * sizeof(float), stream);   // uafT + vafT contiguous (gT_v dead)
    fused_kernel<<<dim3(125, 8, 2), 256, 0, stream>>>(gub, gvb, guT, gvT, inter, uafT, vafT);

    // ---- pools (paired u/v per step) ----
    hipMemsetAsync(pq_u, 0, 1280 * sizeof(float), stream);   // pq_u..pc_v contiguous
    for (int stp = 0; stp < 2; ++stp) {
        gates_pool2_kernel<<<dim3(640, 2), 64, 0, stream>>>(gsWih, gsWhh, gsbih, gsbhh, pq_u, ph_u,
                                                            gvWih, gvWhh, gvbih, gvbhh, pq_v, ph_v, pgts2);
        pool_point2_kernel<<<dim3(1, 2), 256, 0, stream>>>(pgts2, ph_u, pc_u, pq_u, ph_v, pc_v, pq_v);
        pool_scores2_kernel<<<dim3(32, 2), 256, 0, stream>>>(uafT, q_u, ph_u, sc_u, vafT, q_v, ph_v, sc_v, pmax2);
        pool_softmax2_kernel<<<dim3(1, 2), 256, 0, stream>>>(sc_u, sc_v, pmax2, pden2);
        pool_r2_kernel<<<dim3(160, 2), 256, 0, stream>>>(uafT, q_u, sc_u, vafT, q_v, sc_v, pden2, pq_u, pq_v);
    }

    // ---- final MLP ----
    concat_kernel<<<1, 640, 0, stream>>>(pq_u, pq_v, mx0);
    gemv_kernel<<<360, 64, 0, stream>>>(w1, b1, mx0, mx1, 640, 1);
    gemv_kernel<<<200, 64, 0, stream>>>(w2, b2, mx1, mx2, 360, 1);
    gemv_kernel<<<120, 64, 0, stream>>>(w3, b3, mx2, mx3, 200, 1);
    gemv_kernel<<<1, 64, 0, stream>>>(w4, b4, mx3, out, 120, 0);
}